// Round 8
// baseline (1278.011 us; speedup 1.0000x reference)
//
#include <hip/hip_runtime.h>
#include <cstddef>

// ---------- types ----------
typedef _Float16 f16x8 __attribute__((ext_vector_type(8)));
typedef _Float16 f16x4 __attribute__((ext_vector_type(4)));
typedef short    s16x8 __attribute__((ext_vector_type(8)));
typedef short    s16x4 __attribute__((ext_vector_type(4)));
typedef float    f32x4 __attribute__((ext_vector_type(4)));

#define MFMA_F16(a, b, c) __builtin_amdgcn_mfma_f32_16x16x32_f16((a), (b), (c), 0, 0, 0)

constexpr int GB = 512, GT = 256, GF = 64;
constexpr int H1 = 256, H2 = 128, H3 = 64;

#if __has_builtin(__builtin_amdgcn_rcpf)
__device__ __forceinline__ float fast_rcp(float x) { return __builtin_amdgcn_rcpf(x); }
#else
__device__ __forceinline__ float fast_rcp(float x) { return 1.f / x; }
#endif

__device__ __forceinline__ f16x8 ld8(const short* p) {
  return __builtin_bit_cast(f16x8, *(const s16x8*)p);
}
__device__ __forceinline__ f16x4 ld4(const short* p) {
  return __builtin_bit_cast(f16x4, *(const s16x4*)p);
}

// Barrier WITHOUT the vmcnt(0) drain: LDS ordering only, so cross-step global
// prefetches and stores stay in flight.
__device__ __forceinline__ void barrier_nodrain() {
  asm volatile("s_waitcnt lgkmcnt(0)" ::: "memory");
  __builtin_amdgcn_s_barrier();
  asm volatile("" ::: "memory");
}

// ---------- fp32 -> fp16 casts + combined biases, one launch ----------
// bc = b_ih + b_hh for the r,z gates (folded into the projection GEMM), b_ih
// alone for n (the n-gate b_hh term is multiplied by r in the epilogue).
struct CastDesc { const float* src; short* dst; int n; };
struct CastArgs {
  CastDesc d[7];
  const float* bih1; const float* bhh1; float* bc1;
  const float* bih2; const float* bhh2; float* bc2;
};

__global__ void cast_many(CastArgs a) {
  const int tid = blockIdx.x * blockDim.x + threadIdx.x;
  const int stride = gridDim.x * blockDim.x;
#pragma unroll
  for (int j = 0; j < 7; j++) {
    const float* __restrict__ s = a.d[j].src;
    short* __restrict__ o = a.d[j].dst;
    const int n = a.d[j].n;
    for (int i = tid; i < n; i += stride)
      o[i] = __builtin_bit_cast(short, (_Float16)s[i]);
  }
  for (int i = tid; i < 3 * H1; i += stride)
    a.bc1[i] = a.bih1[i] + (i < 2 * H1 ? a.bhh1[i] : 0.f);
  for (int i = tid; i < 3 * H2; i += stride)
    a.bc2[i] = a.bih2[i] + (i < 2 * H2 ? a.bhh2[i] : 0.f);
}

// ---------- projection GEMM body (8 waves, 16 timesteps per wg) ----------
// xg[bt][trel+ti][c][bm] = sum_k A[bt*16+bm][tabs+ti][k] * W[c][k] + biasC[c]
template <int K, int NO, int JT>
__device__ __forceinline__ void g_body(const short* __restrict__ A,
                                       const short* __restrict__ W,
                                       const float* __restrict__ biasC,
                                       short* __restrict__ slot, int TC,
                                       int bt, int trel, int tabs, int tid) {
  constexpr int KC = K / 32;
  constexpr int TT = 16;
  const int lane = tid & 63, wid = tid >> 6;
  const int p = lane & 15, q = lane >> 4;
  const int j0 = wid * 16 * JT;

  f16x8 wb[JT][KC];
  float bc[JT];
#pragma unroll
  for (int jt = 0; jt < JT; jt++) {
    const int col = j0 + jt * 16 + p;
    bc[jt] = biasC[col];
#pragma unroll
    for (int kc = 0; kc < KC; kc++)
      wb[jt][kc] = ld8(W + (size_t)col * K + kc * 32 + q * 8);
  }
  const short* arow = A + ((size_t)(bt * 16 + p) * GT + tabs) * K + q * 8;
  short* outb = slot + ((size_t)bt * TC + trel) * NO * 16;

  f16x8 a0[KC], a1[KC];
#pragma unroll
  for (int kc = 0; kc < KC; kc++) a0[kc] = ld8(arow + kc * 32);

  auto step = [&](int ti, f16x8 (&ac)[KC], f16x8 (&anx)[KC], bool pf) {
    if (pf) {
#pragma unroll
      for (int kc = 0; kc < KC; kc++)
        anx[kc] = ld8(arow + (size_t)(ti + 1) * K + kc * 32);
    }
    f32x4 acc[JT];
#pragma unroll
    for (int jt = 0; jt < JT; jt++)
      acc[jt] = f32x4{bc[jt], bc[jt], bc[jt], bc[jt]};
#pragma unroll
    for (int kc = 0; kc < KC; kc++)
#pragma unroll
      for (int jt = 0; jt < JT; jt++)
        acc[jt] = MFMA_F16(ac[kc], wb[jt][kc], acc[jt]);
    short* ob = outb + (size_t)ti * NO * 16;
#pragma unroll
    for (int jt = 0; jt < JT; jt++) {  // C/D: col = lane&15, row = q*4+r
      const int col = j0 + jt * 16 + p;
      s16x4 v;
#pragma unroll
      for (int r = 0; r < 4; r++)
        v[r] = __builtin_bit_cast(short, (_Float16)acc[jt][r]);
      *(s16x4*)&ob[col * 16 + q * 4] = v;
    }
  };

#pragma unroll 1
  for (int ti = 0; ti < TT; ti += 2) {
    step(ti, a0, a1, true);
    step(ti + 1, a1, a0, ti + 2 < TT);
  }
}

template <int K, int NO, int JT>
__global__ __launch_bounds__(512, 2)
void g_kern(const short* __restrict__ A, const short* __restrict__ W,
            const float* __restrict__ biasC, short* __restrict__ slot,
            int TC, int tbase) {
  const int nty = TC / 16;
  const int bt = blockIdx.x / nty, ty = blockIdx.x - bt * nty;
  g_body<K, NO, JT>(A, W, biasC, slot, TC, bt, ty * 16, tbase + ty * 16, threadIdx.x);
}

// ---------- layer-1 recurrence (8 waves, JT=2, KREG=4 n-gate reg split) ----------
__device__ __forceinline__ void r1_run(const short* __restrict__ xg,
                                       const short* __restrict__ Whh,
                                       const float* __restrict__ bhh,
                                       short* __restrict__ hseq,
                                       float* __restrict__ hstate,
                                       int bt, int t0, int t1, int TC,
                                       short* smem, int tid) {
  constexpr int H = H1, KS = H / 32, KREG = 4, JT = 2;
  constexpr int HP = H + 8, NO = 3 * H;
  constexpr int KLDS = KS - KREG, WNP = KLDS * 32 + 8;

  short* wn = smem;            // [H][WNP] n-gate k-tail
  short* hb = smem + H * WNP;  // [2][16][HP]

  const int lane = tid & 63, wid = tid >> 6;
  const int p = lane & 15, q = lane >> 4;
  const int b0 = bt * 16, j0 = wid * 16 * JT;

  {  // stage n-gate k-tail of Whh into LDS (one-time)
    constexpr int KV = KLDS * 4;
    for (int i = tid; i < H * KV; i += 512) {
      const int row = i / KV, kc = i - row * KV;
      *(s16x8*)&wn[row * WNP + kc * 8] =
          *(const s16x8*)&Whh[(size_t)(2 * H + row) * H + KREG * 32 + kc * 8];
    }
  }
  if (t0 == 0) {
    for (int i = tid; i < 2 * 16 * HP; i += 512) hb[i] = 0;
  } else {
    for (int i = tid; i < 16 * H; i += 512) {
      const int row = i / H, col = i - row * H;
      hb[row * HP + col] =
          __builtin_bit_cast(short, (_Float16)hstate[(size_t)(b0 + row) * H + col]);
    }
  }

  f16x8 wrz[JT][2][KS], wnr[JT][KREG];
  float bhn[JT];
  int wrow[JT];
#pragma unroll
  for (int jt = 0; jt < JT; jt++) {
    const int col = j0 + jt * 16 + p;
#pragma unroll
    for (int g = 0; g < 2; g++)
#pragma unroll
      for (int k = 0; k < KS; k++)
        wrz[jt][g][k] = ld8(Whh + (size_t)(g * H + col) * H + k * 32 + q * 8);
#pragma unroll
    for (int k = 0; k < KREG; k++)
      wnr[jt][k] = ld8(Whh + (size_t)(2 * H + col) * H + k * 32 + q * 8);
    wrow[jt] = col;
    bhn[jt] = bhh[2 * H + col];
  }

  float hprev[JT][4];
#pragma unroll
  for (int jt = 0; jt < JT; jt++)
#pragma unroll
    for (int r = 0; r < 4; r++)
      hprev[jt][r] = (t0 == 0) ? 0.f
                   : hstate[(size_t)(b0 + q * 4 + r) * H + (j0 + jt * 16 + p)];

  const size_t sbase = (size_t)bt * TC * NO * 16;
  int loff[JT][3];
#pragma unroll
  for (int jt = 0; jt < JT; jt++)
#pragma unroll
    for (int g = 0; g < 3; g++)
      loff[jt][g] = (g * H + j0 + jt * 16 + p) * 16 + q * 4;

  f16x4 xb[2][JT][3];
#pragma unroll
  for (int u = 0; u < 2; u++)
#pragma unroll
    for (int jt = 0; jt < JT; jt++)
#pragma unroll
      for (int g = 0; g < 3; g++)
        xb[u][jt][g] = ld4(xg + sbase + (size_t)u * NO * 16 + loff[jt][g]);

  __syncthreads();

  const int steps = t1 - t0;
#pragma unroll 1
  for (int sb = 0; sb < steps; sb += 2) {
#pragma unroll
    for (int u = 0; u < 2; u++) {     // fully unrolled: u compile-time (rule #20)
      const int s = sb + u, t = t0 + s;
      short* hbc = hb + u * 16 * HP;
      short* hbn = hb + (u ^ 1) * 16 * HP;

      f32x4 ar[JT], az[JT], an[JT];
#pragma unroll
      for (int jt = 0; jt < JT; jt++) {
#pragma unroll
        for (int r = 0; r < 4; r++) {
          ar[jt][r] = (float)xb[u][jt][0][r];
          az[jt][r] = (float)xb[u][jt][1][r];
        }
        an[jt] = f32x4{0.f, 0.f, 0.f, 0.f};
      }
#pragma unroll
      for (int k = 0; k < KS; k++) {
        const f16x8 ahk = ld8(&hbc[p * HP + k * 32 + q * 8]);
#pragma unroll
        for (int jt = 0; jt < JT; jt++) {
          ar[jt] = MFMA_F16(ahk, wrz[jt][0][k], ar[jt]);
          az[jt] = MFMA_F16(ahk, wrz[jt][1][k], az[jt]);
          if (k < KREG) {
            an[jt] = MFMA_F16(ahk, wnr[jt][k < KREG ? k : 0], an[jt]);
          } else {
            const f16x8 wnk = ld8(&wn[wrow[jt] * WNP + (k - KREG) * 32 + q * 8]);
            an[jt] = MFMA_F16(ahk, wnk, an[jt]);
          }
        }
      }
      // epilogue (r,z biases pre-folded into xg by g1)
#pragma unroll
      for (int jt = 0; jt < JT; jt++) {
        const int col = j0 + jt * 16 + p;
#pragma unroll
        for (int r = 0; r < 4; r++) {
          const int bm = q * 4 + r;
          const float rg = fast_rcp(1.f + __expf(-ar[jt][r]));
          const float zg = fast_rcp(1.f + __expf(-az[jt][r]));
          const float narg = (float)xb[u][jt][2][r] + rg * (an[jt][r] + bhn[jt]);
          const float e2 = __expf(2.f * narg);
          const float ng = 1.f - 2.f * fast_rcp(e2 + 1.f);  // tanh
          const float hnew = (1.f - zg) * ng + zg * hprev[jt][r];
          hprev[jt][r] = hnew;
          const _Float16 hf = (_Float16)hnew;
          hbn[bm * HP + col] = __builtin_bit_cast(short, hf);
          hseq[((size_t)(b0 + bm) * GT + t) * H + col] = __builtin_bit_cast(short, hf);
        }
      }
      if (t == t1 - 1) {
#pragma unroll
        for (int jt = 0; jt < JT; jt++)
#pragma unroll
          for (int r = 0; r < 4; r++)
            hstate[(size_t)(b0 + q * 4 + r) * H + (j0 + jt * 16 + p)] = hprev[jt][r];
      }
      {  // refill xb[u] for step s+2 (ring has pad for the end overrun)
        const size_t s2 = sbase + (size_t)(s + 2) * NO * 16;
#pragma unroll
        for (int jt = 0; jt < JT; jt++)
#pragma unroll
          for (int g = 0; g < 3; g++)
            xb[u][jt][g] = ld4(xg + s2 + loff[jt][g]);
      }
      barrier_nodrain();
    }
  }
}

// ---------- fused layers 2+3 (round-7-proven; r,z biases folded into xg) ----------
__device__ __forceinline__ void rec23_run(const short* __restrict__ xg2,
                                          const short* __restrict__ Whh2,
                                          const float* __restrict__ bhh2,
                                          const short* __restrict__ Wih3,
                                          const short* __restrict__ Whh3,
                                          const float* __restrict__ bih3,
                                          const float* __restrict__ bhh3,
                                          float* __restrict__ hs2,
                                          float* __restrict__ hs3,
                                          int bt, int t0, int t1, int TC,
                                          short* smem, int tid) {
  constexpr int HP2 = H2 + 8, HP3 = H3 + 8, NO = 3 * H2;
  short* hb2 = smem;                 // [2][16][HP2]
  short* hb3 = smem + 2 * 16 * HP2;  // [2][16][HP3]

  const int lane = tid & 63, wid = tid >> 6;
  const int p = lane & 15, q = lane >> 4;
  const int b0 = bt * 16;
  const int col2 = wid * 16 + p;
  const int col3 = (wid & 3) * 16 + p;
  const bool act3 = wid < 4;

  if (t0 == 0) {
    for (int i = tid; i < 2 * 16 * HP2; i += 512) hb2[i] = 0;
    for (int i = tid; i < 2 * 16 * HP3; i += 512) hb3[i] = 0;
  } else {
    for (int i = tid; i < 16 * H2; i += 512) {
      const int r = i / H2, c = i - r * H2;
      hb2[r * HP2 + c] = __builtin_bit_cast(short, (_Float16)hs2[(size_t)(b0 + r) * H2 + c]);
    }
    for (int i = tid; i < 16 * H3; i += 512) {
      const int r = i / H3, c = i - r * H3;
      hb3[r * HP3 + c] = __builtin_bit_cast(short, (_Float16)hs3[(size_t)(b0 + r) * H3 + c]);
    }
  }

  f16x8 w2[3][4];
#pragma unroll
  for (int g = 0; g < 3; g++)
#pragma unroll
    for (int k = 0; k < 4; k++)
      w2[g][k] = ld8(Whh2 + (size_t)(g * H2 + col2) * H2 + k * 32 + q * 8);
  const float bn2 = bhh2[2 * H2 + col2];

  f16x8 wi3[3][4], wh3[3][2];
  float br3 = 0.f, bz3 = 0.f, bn3x = 0.f, bn3h = 0.f;
  if (act3) {
#pragma unroll
    for (int g = 0; g < 3; g++) {
#pragma unroll
      for (int k = 0; k < 4; k++)
        wi3[g][k] = ld8(Wih3 + (size_t)(g * H3 + col3) * H2 + k * 32 + q * 8);
#pragma unroll
      for (int k = 0; k < 2; k++)
        wh3[g][k] = ld8(Whh3 + (size_t)(g * H3 + col3) * H3 + k * 32 + q * 8);
    }
    br3 = bih3[col3] + bhh3[col3];
    bz3 = bih3[H3 + col3] + bhh3[H3 + col3];
    bn3x = bih3[2 * H3 + col3];
    bn3h = bhh3[2 * H3 + col3];
  }

  float h2p[4], h3p[4];
#pragma unroll
  for (int r = 0; r < 4; r++) {
    h2p[r] = (t0 == 0) ? 0.f : hs2[(size_t)(b0 + q * 4 + r) * H2 + col2];
    h3p[r] = (!act3 || t0 == 0) ? 0.f : hs3[(size_t)(b0 + q * 4 + r) * H3 + col3];
  }

  const size_t sbase = (size_t)bt * TC * NO * 16;
  int loff[3];
#pragma unroll
  for (int g = 0; g < 3; g++) loff[g] = (g * H2 + col2) * 16 + q * 4;
  f16x4 xb[2][3];
#pragma unroll
  for (int u = 0; u < 2; u++)
#pragma unroll
    for (int g = 0; g < 3; g++)
      xb[u][g] = ld4(xg2 + sbase + (size_t)u * NO * 16 + loff[g]);

  __syncthreads();

  const int steps = t1 - t0;
#pragma unroll 1
  for (int sb = 0; sb < steps; sb += 2) {
#pragma unroll
    for (int u = 0; u < 2; ++u) {   // u compile-time (rule #20)
      const int s = sb + u, t = t0 + s;
      // ---- layer 2 (all 8 waves); r,z biases already in xg ----
      f32x4 ar, az, an;
#pragma unroll
      for (int r = 0; r < 4; r++) { ar[r] = (float)xb[u][0][r]; az[r] = (float)xb[u][1][r]; }
      an = f32x4{0.f, 0.f, 0.f, 0.f};
#pragma unroll
      for (int k = 0; k < 4; k++) {
        const f16x8 ahk = ld8(&hb2[(u * 16 + p) * HP2 + k * 32 + q * 8]);
        ar = MFMA_F16(ahk, w2[0][k], ar);
        az = MFMA_F16(ahk, w2[1][k], az);
        an = MFMA_F16(ahk, w2[2][k], an);
      }
#pragma unroll
      for (int r = 0; r < 4; r++) {
        const int bm = q * 4 + r;
        const float rg = fast_rcp(1.f + __expf(-ar[r]));
        const float zg = fast_rcp(1.f + __expf(-az[r]));
        const float narg = (float)xb[u][2][r] + rg * (an[r] + bn2);
        const float e2 = __expf(2.f * narg);
        const float ng = 1.f - 2.f * fast_rcp(e2 + 1.f);  // tanh
        const float hnew = (1.f - zg) * ng + zg * h2p[r];
        h2p[r] = hnew;
        hb2[((u ^ 1) * 16 + bm) * HP2 + col2] = __builtin_bit_cast(short, (_Float16)hnew);
        if (t == t1 - 1) hs2[(size_t)(b0 + bm) * H2 + col2] = hnew;
      }
      {  // refill xb[u] for step s+2
        const size_t s2 = sbase + (size_t)(s + 2) * NO * 16;
#pragma unroll
        for (int g = 0; g < 3; g++) xb[u][g] = ld4(xg2 + s2 + loff[g]);
      }
      barrier_nodrain();  // h2(t) visible; refills + stores stay in flight
      // ---- layer 3 (waves 0-3) ----
      if (act3) {
        f32x4 a3r{0.f,0.f,0.f,0.f}, a3z{0.f,0.f,0.f,0.f},
              a3x{0.f,0.f,0.f,0.f}, a3h{0.f,0.f,0.f,0.f};
#pragma unroll
        for (int k = 0; k < 4; k++) {   // input projection from h2(t) in LDS
          const f16x8 a2k = ld8(&hb2[((u ^ 1) * 16 + p) * HP2 + k * 32 + q * 8]);
          a3r = MFMA_F16(a2k, wi3[0][k], a3r);
          a3z = MFMA_F16(a2k, wi3[1][k], a3z);
          a3x = MFMA_F16(a2k, wi3[2][k], a3x);
        }
#pragma unroll
        for (int k = 0; k < 2; k++) {   // recurrence on h3(t-1)
          const f16x8 a3k = ld8(&hb3[(u * 16 + p) * HP3 + k * 32 + q * 8]);
          a3r = MFMA_F16(a3k, wh3[0][k], a3r);
          a3z = MFMA_F16(a3k, wh3[1][k], a3z);
          a3h = MFMA_F16(a3k, wh3[2][k], a3h);
        }
#pragma unroll
        for (int r = 0; r < 4; r++) {
          const int bm = q * 4 + r;
          const float rg = fast_rcp(1.f + __expf(-(a3r[r] + br3)));
          const float zg = fast_rcp(1.f + __expf(-(a3z[r] + bz3)));
          const float narg = a3x[r] + bn3x + rg * (a3h[r] + bn3h);
          const float e2 = __expf(2.f * narg);
          const float ng = 1.f - 2.f * fast_rcp(e2 + 1.f);
          const float hnew = (1.f - zg) * ng + zg * h3p[r];
          h3p[r] = hnew;
          hb3[((u ^ 1) * 16 + bm) * HP3 + col3] = __builtin_bit_cast(short, (_Float16)hnew);
          if (t == t1 - 1) hs3[(size_t)(b0 + bm) * H3 + col3] = hnew;
        }
      }
    }
  }
}

// ---------- fused launches: recurrence chunk c || projection chunk c+1 ----------
__global__ __launch_bounds__(512, 2)
void fused1(const short* __restrict__ xg_rd, short* __restrict__ xg_wr,
            const short* __restrict__ xh, const short* __restrict__ wih1,
            const float* __restrict__ bc1, const short* __restrict__ whh1,
            const float* __restrict__ bhh1, short* __restrict__ h1,
            float* __restrict__ hs1, int t0, int TC) {
  extern __shared__ __align__(16) short smem[];
  if (blockIdx.x < 32) {
    r1_run(xg_rd, whh1, bhh1, h1, hs1, blockIdx.x, t0, t0 + TC, TC, smem, threadIdx.x);
  } else if (xg_wr) {
    const int g = blockIdx.x - 32, nty = TC / 16;
    const int bt = g / nty, ty = g - bt * nty;
    g_body<GF, 3 * H1, 6>(xh, wih1, bc1, xg_wr, TC, bt, ty * 16,
                          t0 + TC + ty * 16, threadIdx.x);
  }
}

__global__ __launch_bounds__(512, 2)
void fused2(const short* __restrict__ xg_rd, short* __restrict__ xg_wr,
            const short* __restrict__ h1, const short* __restrict__ wih2,
            const float* __restrict__ bc2, const short* __restrict__ whh2,
            const float* __restrict__ bhh2, const short* __restrict__ wih3,
            const short* __restrict__ whh3, const float* __restrict__ bih3,
            const float* __restrict__ bhh3, float* __restrict__ hs2,
            float* __restrict__ hs3, int t0, int TC) {
  extern __shared__ __align__(16) short smem[];
  if (blockIdx.x < 32) {
    rec23_run(xg_rd, whh2, bhh2, wih3, whh3, bih3, bhh3, hs2, hs3,
              blockIdx.x, t0, t0 + TC, TC, smem, threadIdx.x);
  } else if (xg_wr) {
    const int g = blockIdx.x - 32, nty = TC / 16;
    const int bt = g / nty, ty = g - bt * nty;
    g_body<H1, 3 * H2, 3>(h1, wih2, bc2, xg_wr, TC, bt, ty * 16,
                          t0 + TC + ty * 16, threadIdx.x);
  }
}

// ---------- dense head ----------
__global__ void dense_kernel(const float* __restrict__ hl, const float* __restrict__ Wd,
                             const float* __restrict__ bd, float* __restrict__ out) {
  const int b = blockIdx.x * 64 + threadIdx.x;
  float a = bd[0];
#pragma unroll
  for (int k = 0; k < 64; k++) a = fmaf(hl[b * 64 + k], Wd[k], a);
  out[b] = a;
}

// ---------- host ----------
extern "C" void kernel_launch(void* const* d_in, const int* in_sizes, int n_in,
                              void* d_out, int out_size, void* d_ws, size_t ws_size,
                              hipStream_t stream) {
  constexpr int B = GB, T = GT, F = GF;
  constexpr int M = B * T;

  const float* x     = (const float*)d_in[0];
  const float* W_ih1 = (const float*)d_in[1];
  const float* W_hh1 = (const float*)d_in[2];
  const float* b_ih1 = (const float*)d_in[3];
  const float* b_hh1 = (const float*)d_in[4];
  const float* W_ih2 = (const float*)d_in[5];
  const float* W_hh2 = (const float*)d_in[6];
  const float* b_ih2 = (const float*)d_in[7];
  const float* b_hh2 = (const float*)d_in[8];
  const float* W_ih3 = (const float*)d_in[9];
  const float* W_hh3 = (const float*)d_in[10];
  const float* b_ih3 = (const float*)d_in[11];
  const float* b_hh3 = (const float*)d_in[12];
  const float* W_d   = (const float*)d_in[13];
  const float* b_d   = (const float*)d_in[14];
  float* out = (float*)d_out;

  char* ws = (char*)d_ws;
  size_t off = 0;
  auto alloc = [&](size_t bytes) -> char* {
    char* pp = ws + off;
    off = (off + bytes + 255) & ~(size_t)255;
    return pp;
  };

  const int nx    = M * F;
  const int nwih1 = 3 * H1 * F,  nwhh1 = 3 * H1 * H1;
  const int nwih2 = 3 * H2 * H1, nwhh2 = 3 * H2 * H2;
  const int nwih3 = 3 * H3 * H2, nwhh3 = 3 * H3 * H3;

  short* xh   = (short*)alloc((size_t)nx * 2);
  short* wih1 = (short*)alloc((size_t)nwih1 * 2);
  short* whh1 = (short*)alloc((size_t)nwhh1 * 2);
  short* wih2 = (short*)alloc((size_t)nwih2 * 2);
  short* whh2 = (short*)alloc((size_t)nwhh2 * 2);
  short* wih3 = (short*)alloc((size_t)nwih3 * 2);
  short* whh3 = (short*)alloc((size_t)nwhh3 * 2);
  short* h1   = (short*)alloc((size_t)M * H1 * 2);
  float* hs1  = (float*)alloc((size_t)B * H1 * 4);
  float* hs2  = (float*)alloc((size_t)B * H2 * 4);
  float* hs3  = (float*)alloc((size_t)B * H3 * 4);
  float* bc1  = (float*)alloc(3 * H1 * 4);
  float* bc2  = (float*)alloc(3 * H2 * 4);
  (void)n_in; (void)in_sizes; (void)out_size;

  // chunk size: double-buffered rings for xg1 (3H1) and xg2 (3H2), +pads
  const size_t avail = (ws_size > off) ? (ws_size - off) : 0;
  int TC = 64;
  auto need = [&](int tc) -> size_t {
    return (size_t)tc * 1572864 /*ring1*/ + (size_t)tc * 786432 /*ring2*/ + 2 * 65536;
  };
  while (TC > 16 && need(TC) > avail) TC >>= 1;
  const int NC = T / TC, nty = TC / 16;
  const size_t slot1e = (size_t)32 * TC * (3 * H1) * 16;  // elements
  const size_t slot2e = (size_t)32 * TC * (3 * H2) * 16;
  short* ring1 = (short*)alloc(2 * slot1e * 2 + 65536);
  short* ring2 = (short*)alloc(2 * slot2e * 2 + 65536);

  CastArgs ca;
  ca.d[0] = {x, xh, nx};
  ca.d[1] = {W_ih1, wih1, nwih1};
  ca.d[2] = {W_hh1, whh1, nwhh1};
  ca.d[3] = {W_ih2, wih2, nwih2};
  ca.d[4] = {W_hh2, whh2, nwhh2};
  ca.d[5] = {W_ih3, wih3, nwih3};
  ca.d[6] = {W_hh3, whh3, nwhh3};
  ca.bih1 = b_ih1; ca.bhh1 = b_hh1; ca.bc1 = bc1;
  ca.bih2 = b_ih2; ca.bhh2 = b_hh2; ca.bc2 = bc2;
  cast_many<<<1024, 256, 0, stream>>>(ca);

  // LDS: fused1 = wn[256][136] + hb[2][16][264] = 86528 B; fused2 = 13312 B
  constexpr int SM1 = H1 * 136 * 2 + 2 * 16 * (H1 + 8) * 2;
  constexpr int SM2 = 2 * 16 * (H2 + 8) * 2 + 2 * 16 * (H3 + 8) * 2;
  (void)hipFuncSetAttribute((const void*)fused1,
                            hipFuncAttributeMaxDynamicSharedMemorySize, SM1);

  // ---- layer 1: r1(c) || g1(c+1) ----
  g_kern<GF, 3 * H1, 6><<<32 * nty, 512, 0, stream>>>(xh, wih1, bc1, ring1, TC, 0);
  for (int c = 0; c < NC; ++c) {
    const short* rd = ring1 + (size_t)(c & 1) * slot1e;
    short* wr = (c + 1 < NC) ? ring1 + (size_t)((c + 1) & 1) * slot1e : nullptr;
    fused1<<<32 + (wr ? 32 * nty : 0), 512, SM1, stream>>>(
        rd, wr, xh, wih1, bc1, whh1, b_hh1, h1, hs1, c * TC, TC);
  }
  // ---- layers 2+3: rec23(c) || g2(c+1) ----
  g_kern<H1, 3 * H2, 3><<<32 * nty, 512, 0, stream>>>(h1, wih2, bc2, ring2, TC, 0);
  for (int c = 0; c < NC; ++c) {
    const short* rd = ring2 + (size_t)(c & 1) * slot2e;
    short* wr = (c + 1 < NC) ? ring2 + (size_t)((c + 1) & 1) * slot2e : nullptr;
    fused2<<<32 + (wr ? 32 * nty : 0), 512, SM2, stream>>>(
        rd, wr, h1, wih2, bc2, whh2, b_hh2, wih3, whh3, b_ih3, b_hh3,
        hs2, hs3, c * TC, TC);
  }

  dense_kernel<<<B / 64, 64, 0, stream>>>(hs3, W_d, b_d, out);
}

// Round 9
// 1274.965 us; speedup vs baseline: 1.0024x; 1.0024x over previous
//
#include <hip/hip_runtime.h>
#include <cstddef>

// ---------- types ----------
typedef _Float16 f16x8 __attribute__((ext_vector_type(8)));
typedef _Float16 f16x4 __attribute__((ext_vector_type(4)));
typedef short    s16x8 __attribute__((ext_vector_type(8)));
typedef short    s16x4 __attribute__((ext_vector_type(4)));
typedef float    f32x4 __attribute__((ext_vector_type(4)));

#define MFMA_F16(a, b, c) __builtin_amdgcn_mfma_f32_16x16x32_f16((a), (b), (c), 0, 0, 0)

constexpr int GB = 512, GT = 256, GF = 64;
constexpr int H1 = 256, H2 = 128, H3 = 64;

#if __has_builtin(__builtin_amdgcn_rcpf)
__device__ __forceinline__ float fast_rcp(float x) { return __builtin_amdgcn_rcpf(x); }
#else
__device__ __forceinline__ float fast_rcp(float x) { return 1.f / x; }
#endif

__device__ __forceinline__ f16x8 ld8(const short* p) {
  return __builtin_bit_cast(f16x8, *(const s16x8*)p);
}
__device__ __forceinline__ f16x4 ld4(const short* p) {
  return __builtin_bit_cast(f16x4, *(const s16x4*)p);
}

// Barrier WITHOUT the vmcnt(0) drain: LDS ordering only, so cross-step global
// prefetches and stores stay in flight.
__device__ __forceinline__ void barrier_nodrain() {
  asm volatile("s_waitcnt lgkmcnt(0)" ::: "memory");
  __builtin_amdgcn_s_barrier();
  asm volatile("" ::: "memory");
}

// ---------- fp32 -> fp16 casts + combined biases, one launch ----------
// bc = b_ih + b_hh for the r,z gates (folded into the projection GEMM), b_ih
// alone for n (the n-gate b_hh term is multiplied by r in the epilogue).
struct CastDesc { const float* src; short* dst; int n; };
struct CastArgs {
  CastDesc d[7];
  const float* bih1; const float* bhh1; float* bc1;
  const float* bih2; const float* bhh2; float* bc2;
};

__global__ void cast_many(CastArgs a) {
  const int tid = blockIdx.x * blockDim.x + threadIdx.x;
  const int stride = gridDim.x * blockDim.x;
#pragma unroll
  for (int j = 0; j < 7; j++) {
    const float* __restrict__ s = a.d[j].src;
    short* __restrict__ o = a.d[j].dst;
    const int n = a.d[j].n;
    for (int i = tid; i < n; i += stride)
      o[i] = __builtin_bit_cast(short, (_Float16)s[i]);
  }
  for (int i = tid; i < 3 * H1; i += stride)
    a.bc1[i] = a.bih1[i] + (i < 2 * H1 ? a.bhh1[i] : 0.f);
  for (int i = tid; i < 3 * H2; i += stride)
    a.bc2[i] = a.bih2[i] + (i < 2 * H2 ? a.bhh2[i] : 0.f);
}

// ---------- projection GEMM body (8 waves, 16 timesteps per wg) ----------
// xg[bt][trel+ti][c][bm] = sum_k A[bt*16+bm][tabs+ti][k] * W[c][k] + biasC[c]
template <int K, int NO, int JT>
__device__ __forceinline__ void g_body(const short* __restrict__ A,
                                       const short* __restrict__ W,
                                       const float* __restrict__ biasC,
                                       short* __restrict__ slot, int TC,
                                       int bt, int trel, int tabs, int tid) {
  constexpr int KC = K / 32;
  constexpr int TT = 16;
  const int lane = tid & 63, wid = tid >> 6;
  const int p = lane & 15, q = lane >> 4;
  const int j0 = wid * 16 * JT;

  f16x8 wb[JT][KC];
  float bc[JT];
#pragma unroll
  for (int jt = 0; jt < JT; jt++) {
    const int col = j0 + jt * 16 + p;
    bc[jt] = biasC[col];
#pragma unroll
    for (int kc = 0; kc < KC; kc++)
      wb[jt][kc] = ld8(W + (size_t)col * K + kc * 32 + q * 8);
  }
  const short* arow = A + ((size_t)(bt * 16 + p) * GT + tabs) * K + q * 8;
  short* outb = slot + ((size_t)bt * TC + trel) * NO * 16;

  f16x8 a0[KC], a1[KC];
#pragma unroll
  for (int kc = 0; kc < KC; kc++) a0[kc] = ld8(arow + kc * 32);

  auto step = [&](int ti, f16x8 (&ac)[KC], f16x8 (&anx)[KC], bool pf) {
    if (pf) {
#pragma unroll
      for (int kc = 0; kc < KC; kc++)
        anx[kc] = ld8(arow + (size_t)(ti + 1) * K + kc * 32);
    }
    f32x4 acc[JT];
#pragma unroll
    for (int jt = 0; jt < JT; jt++)
      acc[jt] = f32x4{bc[jt], bc[jt], bc[jt], bc[jt]};
#pragma unroll
    for (int kc = 0; kc < KC; kc++)
#pragma unroll
      for (int jt = 0; jt < JT; jt++)
        acc[jt] = MFMA_F16(ac[kc], wb[jt][kc], acc[jt]);
    short* ob = outb + (size_t)ti * NO * 16;
#pragma unroll
    for (int jt = 0; jt < JT; jt++) {  // C/D: col = lane&15, row = q*4+r
      const int col = j0 + jt * 16 + p;
      s16x4 v;
#pragma unroll
      for (int r = 0; r < 4; r++)
        v[r] = __builtin_bit_cast(short, (_Float16)acc[jt][r]);
      *(s16x4*)&ob[col * 16 + q * 4] = v;
    }
  };

#pragma unroll 1
  for (int ti = 0; ti < TT; ti += 2) {
    step(ti, a0, a1, true);
    step(ti + 1, a1, a0, ti + 2 < TT);
  }
}

template <int K, int NO, int JT>
__global__ __launch_bounds__(512, 2)
void g_kern(const short* __restrict__ A, const short* __restrict__ W,
            const float* __restrict__ biasC, short* __restrict__ slot,
            int TC, int tbase) {
  const int nty = TC / 16;
  const int bt = blockIdx.x / nty, ty = blockIdx.x - bt * nty;
  g_body<K, NO, JT>(A, W, biasC, slot, TC, bt, ty * 16, tbase + ty * 16, threadIdx.x);
}

// ---------- layer-1 recurrence (8 waves, JT=2, KREG=4 n-gate reg split) ----------
__device__ __forceinline__ void r1_run(const short* __restrict__ xg,
                                       const short* __restrict__ Whh,
                                       const float* __restrict__ bhh,
                                       short* __restrict__ hseq,
                                       float* __restrict__ hstate,
                                       int bt, int t0, int t1, int TC,
                                       short* smem, int tid) {
  constexpr int H = H1, KS = H / 32, KREG = 4, JT = 2;
  constexpr int HP = H + 8, NO = 3 * H;
  constexpr int KLDS = KS - KREG, WNP = KLDS * 32 + 8;

  short* wn = smem;            // [H][WNP] n-gate k-tail
  short* hb = smem + H * WNP;  // [2][16][HP]

  const int lane = tid & 63, wid = tid >> 6;
  const int p = lane & 15, q = lane >> 4;
  const int b0 = bt * 16, j0 = wid * 16 * JT;

  {  // stage n-gate k-tail of Whh into LDS (one-time)
    constexpr int KV = KLDS * 4;
    for (int i = tid; i < H * KV; i += 512) {
      const int row = i / KV, kc = i - row * KV;
      *(s16x8*)&wn[row * WNP + kc * 8] =
          *(const s16x8*)&Whh[(size_t)(2 * H + row) * H + KREG * 32 + kc * 8];
    }
  }
  if (t0 == 0) {
    for (int i = tid; i < 2 * 16 * HP; i += 512) hb[i] = 0;
  } else {
    for (int i = tid; i < 16 * H; i += 512) {
      const int row = i / H, col = i - row * H;
      hb[row * HP + col] =
          __builtin_bit_cast(short, (_Float16)hstate[(size_t)(b0 + row) * H + col]);
    }
  }

  f16x8 wrz[JT][2][KS], wnr[JT][KREG];
  float bhn[JT];
  int wrow[JT];
#pragma unroll
  for (int jt = 0; jt < JT; jt++) {
    const int col = j0 + jt * 16 + p;
#pragma unroll
    for (int g = 0; g < 2; g++)
#pragma unroll
      for (int k = 0; k < KS; k++)
        wrz[jt][g][k] = ld8(Whh + (size_t)(g * H + col) * H + k * 32 + q * 8);
#pragma unroll
    for (int k = 0; k < KREG; k++)
      wnr[jt][k] = ld8(Whh + (size_t)(2 * H + col) * H + k * 32 + q * 8);
    wrow[jt] = col;
    bhn[jt] = bhh[2 * H + col];
  }

  float hprev[JT][4];
#pragma unroll
  for (int jt = 0; jt < JT; jt++)
#pragma unroll
    for (int r = 0; r < 4; r++)
      hprev[jt][r] = (t0 == 0) ? 0.f
                   : hstate[(size_t)(b0 + q * 4 + r) * H + (j0 + jt * 16 + p)];

  const size_t sbase = (size_t)bt * TC * NO * 16;
  int loff[JT][3];
#pragma unroll
  for (int jt = 0; jt < JT; jt++)
#pragma unroll
    for (int g = 0; g < 3; g++)
      loff[jt][g] = (g * H + j0 + jt * 16 + p) * 16 + q * 4;

  f16x4 xb[2][JT][3];
#pragma unroll
  for (int u = 0; u < 2; u++)
#pragma unroll
    for (int jt = 0; jt < JT; jt++)
#pragma unroll
      for (int g = 0; g < 3; g++)
        xb[u][jt][g] = ld4(xg + sbase + (size_t)u * NO * 16 + loff[jt][g]);

  __syncthreads();

  const int steps = t1 - t0;
#pragma unroll 1
  for (int sb = 0; sb < steps; sb += 2) {
#pragma unroll
    for (int u = 0; u < 2; u++) {     // fully unrolled: u compile-time (rule #20)
      const int s = sb + u, t = t0 + s;
      short* hbc = hb + u * 16 * HP;
      short* hbn = hb + (u ^ 1) * 16 * HP;

      f32x4 ar[JT], az[JT], an[JT];
#pragma unroll
      for (int jt = 0; jt < JT; jt++) {
#pragma unroll
        for (int r = 0; r < 4; r++) {
          ar[jt][r] = (float)xb[u][jt][0][r];
          az[jt][r] = (float)xb[u][jt][1][r];
        }
        an[jt] = f32x4{0.f, 0.f, 0.f, 0.f};
      }
#pragma unroll
      for (int k = 0; k < KS; k++) {
        const f16x8 ahk = ld8(&hbc[p * HP + k * 32 + q * 8]);
#pragma unroll
        for (int jt = 0; jt < JT; jt++) {
          ar[jt] = MFMA_F16(ahk, wrz[jt][0][k], ar[jt]);
          az[jt] = MFMA_F16(ahk, wrz[jt][1][k], az[jt]);
          if (k < KREG) {
            an[jt] = MFMA_F16(ahk, wnr[jt][k < KREG ? k : 0], an[jt]);
          } else {
            const f16x8 wnk = ld8(&wn[wrow[jt] * WNP + (k - KREG) * 32 + q * 8]);
            an[jt] = MFMA_F16(ahk, wnk, an[jt]);
          }
        }
      }
      // epilogue (r,z biases pre-folded into xg by g1)
#pragma unroll
      for (int jt = 0; jt < JT; jt++) {
        const int col = j0 + jt * 16 + p;
#pragma unroll
        for (int r = 0; r < 4; r++) {
          const int bm = q * 4 + r;
          const float rg = fast_rcp(1.f + __expf(-ar[jt][r]));
          const float zg = fast_rcp(1.f + __expf(-az[jt][r]));
          const float narg = (float)xb[u][jt][2][r] + rg * (an[jt][r] + bhn[jt]);
          const float e2 = __expf(2.f * narg);
          const float ng = 1.f - 2.f * fast_rcp(e2 + 1.f);  // tanh
          const float hnew = (1.f - zg) * ng + zg * hprev[jt][r];
          hprev[jt][r] = hnew;
          const _Float16 hf = (_Float16)hnew;
          hbn[bm * HP + col] = __builtin_bit_cast(short, hf);
          hseq[((size_t)(b0 + bm) * GT + t) * H + col] = __builtin_bit_cast(short, hf);
        }
      }
      if (t == t1 - 1) {
#pragma unroll
        for (int jt = 0; jt < JT; jt++)
#pragma unroll
          for (int r = 0; r < 4; r++)
            hstate[(size_t)(b0 + q * 4 + r) * H + (j0 + jt * 16 + p)] = hprev[jt][r];
      }
      {  // refill xb[u] for step s+2 (ring has pad for the end overrun)
        const size_t s2 = sbase + (size_t)(s + 2) * NO * 16;
#pragma unroll
        for (int jt = 0; jt < JT; jt++)
#pragma unroll
          for (int g = 0; g < 3; g++)
            xb[u][jt][g] = ld4(xg + s2 + loff[jt][g]);
      }
      barrier_nodrain();
    }
  }
}

// ---------- fused layers 2+3 (round-7-proven; r,z biases folded into xg) ----------
__device__ __forceinline__ void rec23_run(const short* __restrict__ xg2,
                                          const short* __restrict__ Whh2,
                                          const float* __restrict__ bhh2,
                                          const short* __restrict__ Wih3,
                                          const short* __restrict__ Whh3,
                                          const float* __restrict__ bih3,
                                          const float* __restrict__ bhh3,
                                          float* __restrict__ hs2,
                                          float* __restrict__ hs3,
                                          int bt, int t0, int t1, int TC,
                                          short* smem, int tid) {
  constexpr int HP2 = H2 + 8, HP3 = H3 + 8, NO = 3 * H2;
  short* hb2 = smem;                 // [2][16][HP2]
  short* hb3 = smem + 2 * 16 * HP2;  // [2][16][HP3]

  const int lane = tid & 63, wid = tid >> 6;
  const int p = lane & 15, q = lane >> 4;
  const int b0 = bt * 16;
  const int col2 = wid * 16 + p;
  const int col3 = (wid & 3) * 16 + p;
  const bool act3 = wid < 4;

  if (t0 == 0) {
    for (int i = tid; i < 2 * 16 * HP2; i += 512) hb2[i] = 0;
    for (int i = tid; i < 2 * 16 * HP3; i += 512) hb3[i] = 0;
  } else {
    for (int i = tid; i < 16 * H2; i += 512) {
      const int r = i / H2, c = i - r * H2;
      hb2[r * HP2 + c] = __builtin_bit_cast(short, (_Float16)hs2[(size_t)(b0 + r) * H2 + c]);
    }
    for (int i = tid; i < 16 * H3; i += 512) {
      const int r = i / H3, c = i - r * H3;
      hb3[r * HP3 + c] = __builtin_bit_cast(short, (_Float16)hs3[(size_t)(b0 + r) * H3 + c]);
    }
  }

  f16x8 w2[3][4];
#pragma unroll
  for (int g = 0; g < 3; g++)
#pragma unroll
    for (int k = 0; k < 4; k++)
      w2[g][k] = ld8(Whh2 + (size_t)(g * H2 + col2) * H2 + k * 32 + q * 8);
  const float bn2 = bhh2[2 * H2 + col2];

  f16x8 wi3[3][4], wh3[3][2];
  float br3 = 0.f, bz3 = 0.f, bn3x = 0.f, bn3h = 0.f;
  if (act3) {
#pragma unroll
    for (int g = 0; g < 3; g++) {
#pragma unroll
      for (int k = 0; k < 4; k++)
        wi3[g][k] = ld8(Wih3 + (size_t)(g * H3 + col3) * H2 + k * 32 + q * 8);
#pragma unroll
      for (int k = 0; k < 2; k++)
        wh3[g][k] = ld8(Whh3 + (size_t)(g * H3 + col3) * H3 + k * 32 + q * 8);
    }
    br3 = bih3[col3] + bhh3[col3];
    bz3 = bih3[H3 + col3] + bhh3[H3 + col3];
    bn3x = bih3[2 * H3 + col3];
    bn3h = bhh3[2 * H3 + col3];
  }

  float h2p[4], h3p[4];
#pragma unroll
  for (int r = 0; r < 4; r++) {
    h2p[r] = (t0 == 0) ? 0.f : hs2[(size_t)(b0 + q * 4 + r) * H2 + col2];
    h3p[r] = (!act3 || t0 == 0) ? 0.f : hs3[(size_t)(b0 + q * 4 + r) * H3 + col3];
  }

  const size_t sbase = (size_t)bt * TC * NO * 16;
  int loff[3];
#pragma unroll
  for (int g = 0; g < 3; g++) loff[g] = (g * H2 + col2) * 16 + q * 4;
  f16x4 xb[2][3];
#pragma unroll
  for (int u = 0; u < 2; u++)
#pragma unroll
    for (int g = 0; g < 3; g++)
      xb[u][g] = ld4(xg2 + sbase + (size_t)u * NO * 16 + loff[g]);

  __syncthreads();

  const int steps = t1 - t0;
#pragma unroll 1
  for (int sb = 0; sb < steps; sb += 2) {
#pragma unroll
    for (int u = 0; u < 2; ++u) {   // u compile-time (rule #20)
      const int s = sb + u, t = t0 + s;
      // ---- layer 2 (all 8 waves); r,z biases already in xg ----
      f32x4 ar, az, an;
#pragma unroll
      for (int r = 0; r < 4; r++) { ar[r] = (float)xb[u][0][r]; az[r] = (float)xb[u][1][r]; }
      an = f32x4{0.f, 0.f, 0.f, 0.f};
#pragma unroll
      for (int k = 0; k < 4; k++) {
        const f16x8 ahk = ld8(&hb2[(u * 16 + p) * HP2 + k * 32 + q * 8]);
        ar = MFMA_F16(ahk, w2[0][k], ar);
        az = MFMA_F16(ahk, w2[1][k], az);
        an = MFMA_F16(ahk, w2[2][k], an);
      }
#pragma unroll
      for (int r = 0; r < 4; r++) {
        const int bm = q * 4 + r;
        const float rg = fast_rcp(1.f + __expf(-ar[r]));
        const float zg = fast_rcp(1.f + __expf(-az[r]));
        const float narg = (float)xb[u][2][r] + rg * (an[r] + bn2);
        const float e2 = __expf(2.f * narg);
        const float ng = 1.f - 2.f * fast_rcp(e2 + 1.f);  // tanh
        const float hnew = (1.f - zg) * ng + zg * h2p[r];
        h2p[r] = hnew;
        hb2[((u ^ 1) * 16 + bm) * HP2 + col2] = __builtin_bit_cast(short, (_Float16)hnew);
        if (t == t1 - 1) hs2[(size_t)(b0 + bm) * H2 + col2] = hnew;
      }
      {  // refill xb[u] for step s+2
        const size_t s2 = sbase + (size_t)(s + 2) * NO * 16;
#pragma unroll
        for (int g = 0; g < 3; g++) xb[u][g] = ld4(xg2 + s2 + loff[g]);
      }
      barrier_nodrain();  // h2(t) visible; refills + stores stay in flight
      // ---- layer 3 (waves 0-3) ----
      if (act3) {
        f32x4 a3r{0.f,0.f,0.f,0.f}, a3z{0.f,0.f,0.f,0.f},
              a3x{0.f,0.f,0.f,0.f}, a3h{0.f,0.f,0.f,0.f};
#pragma unroll
        for (int k = 0; k < 4; k++) {   // input projection from h2(t) in LDS
          const f16x8 a2k = ld8(&hb2[((u ^ 1) * 16 + p) * HP2 + k * 32 + q * 8]);
          a3r = MFMA_F16(a2k, wi3[0][k], a3r);
          a3z = MFMA_F16(a2k, wi3[1][k], a3z);
          a3x = MFMA_F16(a2k, wi3[2][k], a3x);
        }
#pragma unroll
        for (int k = 0; k < 2; k++) {   // recurrence on h3(t-1)
          const f16x8 a3k = ld8(&hb3[(u * 16 + p) * HP3 + k * 32 + q * 8]);
          a3r = MFMA_F16(a3k, wh3[0][k], a3r);
          a3z = MFMA_F16(a3k, wh3[1][k], a3z);
          a3h = MFMA_F16(a3k, wh3[2][k], a3h);
        }
#pragma unroll
        for (int r = 0; r < 4; r++) {
          const int bm = q * 4 + r;
          const float rg = fast_rcp(1.f + __expf(-(a3r[r] + br3)));
          const float zg = fast_rcp(1.f + __expf(-(a3z[r] + bz3)));
          const float narg = a3x[r] + bn3x + rg * (a3h[r] + bn3h);
          const float e2 = __expf(2.f * narg);
          const float ng = 1.f - 2.f * fast_rcp(e2 + 1.f);
          const float hnew = (1.f - zg) * ng + zg * h3p[r];
          h3p[r] = hnew;
          hb3[((u ^ 1) * 16 + bm) * HP3 + col3] = __builtin_bit_cast(short, (_Float16)hnew);
          if (t == t1 - 1) hs3[(size_t)(b0 + bm) * H3 + col3] = hnew;
        }
      }
    }
  }
}

// ---------- fused launches: recurrence chunk c || projection chunk c+1 ----------
// launch_bounds(512, 1): min 1 wave/EU -> unified VGPR+AGPR cap 512 (vs 256 at
// min-2). r1's weight set (wrz 128 + wnr 32 AGPR + ~128 VGPR) needs ~290 regs;
// at (512,2) it spilled every step (round 8: 3.3us/step). Occupancy unchanged:
// the 86.5KB LDS already limits to 1 wg/CU.
__global__ __launch_bounds__(512, 1)
void fused1(const short* __restrict__ xg_rd, short* __restrict__ xg_wr,
            const short* __restrict__ xh, const short* __restrict__ wih1,
            const float* __restrict__ bc1, const short* __restrict__ whh1,
            const float* __restrict__ bhh1, short* __restrict__ h1,
            float* __restrict__ hs1, int t0, int TC) {
  extern __shared__ __align__(16) short smem[];
  if (blockIdx.x < 32) {
    r1_run(xg_rd, whh1, bhh1, h1, hs1, blockIdx.x, t0, t0 + TC, TC, smem, threadIdx.x);
  } else if (xg_wr) {
    const int g = blockIdx.x - 32, nty = TC / 16;
    const int bt = g / nty, ty = g - bt * nty;
    g_body<GF, 3 * H1, 6>(xh, wih1, bc1, xg_wr, TC, bt, ty * 16,
                          t0 + TC + ty * 16, threadIdx.x);
  }
}

__global__ __launch_bounds__(512, 2)
void fused2(const short* __restrict__ xg_rd, short* __restrict__ xg_wr,
            const short* __restrict__ h1, const short* __restrict__ wih2,
            const float* __restrict__ bc2, const short* __restrict__ whh2,
            const float* __restrict__ bhh2, const short* __restrict__ wih3,
            const short* __restrict__ whh3, const float* __restrict__ bih3,
            const float* __restrict__ bhh3, float* __restrict__ hs2,
            float* __restrict__ hs3, int t0, int TC) {
  extern __shared__ __align__(16) short smem[];
  if (blockIdx.x < 32) {
    rec23_run(xg_rd, whh2, bhh2, wih3, whh3, bih3, bhh3, hs2, hs3,
              blockIdx.x, t0, t0 + TC, TC, smem, threadIdx.x);
  } else if (xg_wr) {
    const int g = blockIdx.x - 32, nty = TC / 16;
    const int bt = g / nty, ty = g - bt * nty;
    g_body<H1, 3 * H2, 3>(h1, wih2, bc2, xg_wr, TC, bt, ty * 16,
                          t0 + TC + ty * 16, threadIdx.x);
  }
}

// ---------- dense head ----------
__global__ void dense_kernel(const float* __restrict__ hl, const float* __restrict__ Wd,
                             const float* __restrict__ bd, float* __restrict__ out) {
  const int b = blockIdx.x * 64 + threadIdx.x;
  float a = bd[0];
#pragma unroll
  for (int k = 0; k < 64; k++) a = fmaf(hl[b * 64 + k], Wd[k], a);
  out[b] = a;
}

// ---------- host ----------
extern "C" void kernel_launch(void* const* d_in, const int* in_sizes, int n_in,
                              void* d_out, int out_size, void* d_ws, size_t ws_size,
                              hipStream_t stream) {
  constexpr int B = GB, T = GT, F = GF;
  constexpr int M = B * T;

  const float* x     = (const float*)d_in[0];
  const float* W_ih1 = (const float*)d_in[1];
  const float* W_hh1 = (const float*)d_in[2];
  const float* b_ih1 = (const float*)d_in[3];
  const float* b_hh1 = (const float*)d_in[4];
  const float* W_ih2 = (const float*)d_in[5];
  const float* W_hh2 = (const float*)d_in[6];
  const float* b_ih2 = (const float*)d_in[7];
  const float* b_hh2 = (const float*)d_in[8];
  const float* W_ih3 = (const float*)d_in[9];
  const float* W_hh3 = (const float*)d_in[10];
  const float* b_ih3 = (const float*)d_in[11];
  const float* b_hh3 = (const float*)d_in[12];
  const float* W_d   = (const float*)d_in[13];
  const float* b_d   = (const float*)d_in[14];
  float* out = (float*)d_out;

  char* ws = (char*)d_ws;
  size_t off = 0;
  auto alloc = [&](size_t bytes) -> char* {
    char* pp = ws + off;
    off = (off + bytes + 255) & ~(size_t)255;
    return pp;
  };

  const int nx    = M * F;
  const int nwih1 = 3 * H1 * F,  nwhh1 = 3 * H1 * H1;
  const int nwih2 = 3 * H2 * H1, nwhh2 = 3 * H2 * H2;
  const int nwih3 = 3 * H3 * H2, nwhh3 = 3 * H3 * H3;

  short* xh   = (short*)alloc((size_t)nx * 2);
  short* wih1 = (short*)alloc((size_t)nwih1 * 2);
  short* whh1 = (short*)alloc((size_t)nwhh1 * 2);
  short* wih2 = (short*)alloc((size_t)nwih2 * 2);
  short* whh2 = (short*)alloc((size_t)nwhh2 * 2);
  short* wih3 = (short*)alloc((size_t)nwih3 * 2);
  short* whh3 = (short*)alloc((size_t)nwhh3 * 2);
  short* h1   = (short*)alloc((size_t)M * H1 * 2);
  float* hs1  = (float*)alloc((size_t)B * H1 * 4);
  float* hs2  = (float*)alloc((size_t)B * H2 * 4);
  float* hs3  = (float*)alloc((size_t)B * H3 * 4);
  float* bc1  = (float*)alloc(3 * H1 * 4);
  float* bc2  = (float*)alloc(3 * H2 * 4);
  (void)n_in; (void)in_sizes; (void)out_size;

  // chunk size: double-buffered rings for xg1 (3H1) and xg2 (3H2), +pads
  const size_t avail = (ws_size > off) ? (ws_size - off) : 0;
  int TC = 64;
  auto need = [&](int tc) -> size_t {
    return (size_t)tc * 1572864 /*ring1*/ + (size_t)tc * 786432 /*ring2*/ + 2 * 65536;
  };
  while (TC > 16 && need(TC) > avail) TC >>= 1;
  const int NC = T / TC, nty = TC / 16;
  const size_t slot1e = (size_t)32 * TC * (3 * H1) * 16;  // elements
  const size_t slot2e = (size_t)32 * TC * (3 * H2) * 16;
  short* ring1 = (short*)alloc(2 * slot1e * 2 + 65536);
  short* ring2 = (short*)alloc(2 * slot2e * 2 + 65536);

  CastArgs ca;
  ca.d[0] = {x, xh, nx};
  ca.d[1] = {W_ih1, wih1, nwih1};
  ca.d[2] = {W_hh1, whh1, nwhh1};
  ca.d[3] = {W_ih2, wih2, nwih2};
  ca.d[4] = {W_hh2, whh2, nwhh2};
  ca.d[5] = {W_ih3, wih3, nwih3};
  ca.d[6] = {W_hh3, whh3, nwhh3};
  ca.bih1 = b_ih1; ca.bhh1 = b_hh1; ca.bc1 = bc1;
  ca.bih2 = b_ih2; ca.bhh2 = b_hh2; ca.bc2 = bc2;
  cast_many<<<1024, 256, 0, stream>>>(ca);

  // LDS: fused1 = wn[256][136] + hb[2][16][264] = 86528 B; fused2 = 13312 B
  constexpr int SM1 = H1 * 136 * 2 + 2 * 16 * (H1 + 8) * 2;
  constexpr int SM2 = 2 * 16 * (H2 + 8) * 2 + 2 * 16 * (H3 + 8) * 2;
  (void)hipFuncSetAttribute((const void*)fused1,
                            hipFuncAttributeMaxDynamicSharedMemorySize, SM1);

  // ---- layer 1: r1(c) || g1(c+1) ----
  g_kern<GF, 3 * H1, 6><<<32 * nty, 512, 0, stream>>>(xh, wih1, bc1, ring1, TC, 0);
  for (int c = 0; c < NC; ++c) {
    const short* rd = ring1 + (size_t)(c & 1) * slot1e;
    short* wr = (c + 1 < NC) ? ring1 + (size_t)((c + 1) & 1) * slot1e : nullptr;
    fused1<<<32 + (wr ? 32 * nty : 0), 512, SM1, stream>>>(
        rd, wr, xh, wih1, bc1, whh1, b_hh1, h1, hs1, c * TC, TC);
  }
  // ---- layers 2+3: rec23(c) || g2(c+1) ----
  g_kern<H1, 3 * H2, 3><<<32 * nty, 512, 0, stream>>>(h1, wih2, bc2, ring2, TC, 0);
  for (int c = 0; c < NC; ++c) {
    const short* rd = ring2 + (size_t)(c & 1) * slot2e;
    short* wr = (c + 1 < NC) ? ring2 + (size_t)((c + 1) & 1) * slot2e : nullptr;
    fused2<<<32 + (wr ? 32 * nty : 0), 512, SM2, stream>>>(
        rd, wr, h1, wih2, bc2, whh2, b_hh2, wih3, whh3, b_ih3, b_hh3,
        hs2, hs3, c * TC, TC);
  }

  dense_kernel<<<B / 64, 64, 0, stream>>>(hs3, W_d, b_d, out);
}

// Round 10
// 940.012 us; speedup vs baseline: 1.3596x; 1.3563x over previous
//
#include <hip/hip_runtime.h>
#include <cstddef>

// ---------- types ----------
typedef _Float16 f16x8 __attribute__((ext_vector_type(8)));
typedef _Float16 f16x4 __attribute__((ext_vector_type(4)));
typedef short    s16x8 __attribute__((ext_vector_type(8)));
typedef short    s16x4 __attribute__((ext_vector_type(4)));
typedef float    f32x4 __attribute__((ext_vector_type(4)));

#define MFMA_F16(a, b, c) __builtin_amdgcn_mfma_f32_16x16x32_f16((a), (b), (c), 0, 0, 0)

constexpr int GB = 512, GT = 256, GF = 64;
constexpr int H1 = 256, H2 = 128, H3 = 64;

#if __has_builtin(__builtin_amdgcn_rcpf)
__device__ __forceinline__ float fast_rcp(float x) { return __builtin_amdgcn_rcpf(x); }
#else
__device__ __forceinline__ float fast_rcp(float x) { return 1.f / x; }
#endif

__device__ __forceinline__ f16x8 ld8(const short* p) {
  return __builtin_bit_cast(f16x8, *(const s16x8*)p);
}
__device__ __forceinline__ f16x4 ld4(const short* p) {
  return __builtin_bit_cast(f16x4, *(const s16x4*)p);
}

// Barrier WITHOUT the vmcnt(0) drain: LDS ordering only, so cross-step global
// prefetches and stores stay in flight.
__device__ __forceinline__ void barrier_nodrain() {
  asm volatile("s_waitcnt lgkmcnt(0)" ::: "memory");
  __builtin_amdgcn_s_barrier();
  asm volatile("" ::: "memory");
}

// ---------- fp32 -> fp16 casts + layer-2 combined bias, one launch ----------
// Layer 1 uses b_ih directly (round-7 revert); layer 2 keeps the r,z fold.
struct CastDesc { const float* src; short* dst; int n; };
struct CastArgs {
  CastDesc d[7];
  const float* bih2; const float* bhh2; float* bc2;
};

__global__ void cast_many(CastArgs a) {
  const int tid = blockIdx.x * blockDim.x + threadIdx.x;
  const int stride = gridDim.x * blockDim.x;
#pragma unroll
  for (int j = 0; j < 7; j++) {
    const float* __restrict__ s = a.d[j].src;
    short* __restrict__ o = a.d[j].dst;
    const int n = a.d[j].n;
    for (int i = tid; i < n; i += stride)
      o[i] = __builtin_bit_cast(short, (_Float16)s[i]);
  }
  for (int i = tid; i < 3 * H2; i += stride)
    a.bc2[i] = a.bih2[i] + (i < 2 * H2 ? a.bhh2[i] : 0.f);
}

// ---------- projection GEMM body (8 waves, 16 timesteps per wg) ----------
// xg[bt][trel+ti][c][bm] = sum_k A[bt*16+bm][tabs+ti][k] * W[c][k] + biasC[c]
template <int K, int NO, int JT>
__device__ __forceinline__ void g_body(const short* __restrict__ A,
                                       const short* __restrict__ W,
                                       const float* __restrict__ biasC,
                                       short* __restrict__ slot, int TC,
                                       int bt, int trel, int tabs, int tid) {
  constexpr int KC = K / 32;
  constexpr int TT = 16;
  const int lane = tid & 63, wid = tid >> 6;
  const int p = lane & 15, q = lane >> 4;
  const int j0 = wid * 16 * JT;

  f16x8 wb[JT][KC];
  float bc[JT];
#pragma unroll
  for (int jt = 0; jt < JT; jt++) {
    const int col = j0 + jt * 16 + p;
    bc[jt] = biasC[col];
#pragma unroll
    for (int kc = 0; kc < KC; kc++)
      wb[jt][kc] = ld8(W + (size_t)col * K + kc * 32 + q * 8);
  }
  const short* arow = A + ((size_t)(bt * 16 + p) * GT + tabs) * K + q * 8;
  short* outb = slot + ((size_t)bt * TC + trel) * NO * 16;

  f16x8 a0[KC], a1[KC];
#pragma unroll
  for (int kc = 0; kc < KC; kc++) a0[kc] = ld8(arow + kc * 32);

  auto step = [&](int ti, f16x8 (&ac)[KC], f16x8 (&anx)[KC], bool pf) {
    if (pf) {
#pragma unroll
      for (int kc = 0; kc < KC; kc++)
        anx[kc] = ld8(arow + (size_t)(ti + 1) * K + kc * 32);
    }
    f32x4 acc[JT];
#pragma unroll
    for (int jt = 0; jt < JT; jt++)
      acc[jt] = f32x4{bc[jt], bc[jt], bc[jt], bc[jt]};
#pragma unroll
    for (int kc = 0; kc < KC; kc++)
#pragma unroll
      for (int jt = 0; jt < JT; jt++)
        acc[jt] = MFMA_F16(ac[kc], wb[jt][kc], acc[jt]);
    short* ob = outb + (size_t)ti * NO * 16;
#pragma unroll
    for (int jt = 0; jt < JT; jt++) {  // C/D: col = lane&15, row = q*4+r
      const int col = j0 + jt * 16 + p;
      s16x4 v;
#pragma unroll
      for (int r = 0; r < 4; r++)
        v[r] = __builtin_bit_cast(short, (_Float16)acc[jt][r]);
      *(s16x4*)&ob[col * 16 + q * 4] = v;
    }
  };

#pragma unroll 1
  for (int ti = 0; ti < TT; ti += 2) {
    step(ti, a0, a1, true);
    step(ti + 1, a1, a0, ti + 2 < TT);
  }
}

template <int K, int NO, int JT>
__global__ __launch_bounds__(512, 2)
void g_kern(const short* __restrict__ A, const short* __restrict__ W,
            const float* __restrict__ biasC, short* __restrict__ slot,
            int TC, int tbase) {
  const int nty = TC / 16;
  const int bt = blockIdx.x / nty, ty = blockIdx.x - bt * nty;
  g_body<K, NO, JT>(A, W, biasC, slot, TC, bt, ty * 16, tbase + ty * 16, threadIdx.x);
}

// ---------- layer-1 recurrence: EXACT round-7 gru_rec body ----------
// (ablation revert: full n-gate in LDS [256][264], wr[2][2][8] r,z in regs,
// unfolded b_hh biases in epilogue, unconditional 2-deep xg refill)
__device__ __forceinline__ void r1_run(const short* __restrict__ xg,
                                       const short* __restrict__ Whh,
                                       const float* __restrict__ bhh,
                                       short* __restrict__ hseq,
                                       float* __restrict__ hstate,
                                       int bt, int t0, int t1, int TC,
                                       short* smem, int tid) {
  constexpr int H = H1, KS = H / 32, JT = 2;
  constexpr int HP = H + 8, NO = 3 * H;

  short* wn = smem;            // [H][HP] full n-gate Whh
  short* hb = smem + H * HP;   // [2][16][HP]

  const int lane = tid & 63, wid = tid >> 6;
  const int p = lane & 15, q = lane >> 4;
  const int b0 = bt * 16, j0 = wid * 16 * JT;

  {  // stage n-gate rows of Whh into LDS (one-time per chunk)
    constexpr int KV = H / 8;
    for (int i = tid; i < H * KV; i += 512) {
      const int row = i / KV, kc = i - row * KV;
      *(s16x8*)&wn[row * HP + kc * 8] =
          *(const s16x8*)&Whh[(size_t)(2 * H + row) * H + kc * 8];
    }
  }
  if (t0 == 0) {
    for (int i = tid; i < 16 * HP; i += 512) hb[i] = 0;
  } else {
    for (int i = tid; i < 16 * H; i += 512) {
      const int row = i / H, col = i - row * H;
      hb[row * HP + col] =
          __builtin_bit_cast(short, (_Float16)hstate[(size_t)(b0 + row) * H + col]);
    }
  }

  f16x8 wr[JT][2][KS];
#pragma unroll
  for (int jt = 0; jt < JT; jt++) {
    const int col = j0 + jt * 16 + p;
#pragma unroll
    for (int g = 0; g < 2; g++)
#pragma unroll
      for (int k = 0; k < KS; k++)
        wr[jt][g][k] = ld8(Whh + (size_t)(g * H + col) * H + k * 32 + q * 8);
  }
  float bhr[JT], bhz[JT], bhn[JT];
  int wrow[JT];
#pragma unroll
  for (int jt = 0; jt < JT; jt++) {
    const int col = j0 + jt * 16 + p;
    wrow[jt] = col;
    bhr[jt] = bhh[col];
    bhz[jt] = bhh[H + col];
    bhn[jt] = bhh[2 * H + col];
  }

  float hprev[JT][4];
#pragma unroll
  for (int jt = 0; jt < JT; jt++)
#pragma unroll
    for (int r = 0; r < 4; r++)
      hprev[jt][r] = (t0 == 0) ? 0.f
                   : hstate[(size_t)(b0 + q * 4 + r) * H + (j0 + jt * 16 + p)];

  const size_t sbase = (size_t)bt * TC * NO * 16;
  int loff[JT][3];
#pragma unroll
  for (int jt = 0; jt < JT; jt++)
#pragma unroll
    for (int g = 0; g < 3; g++)
      loff[jt][g] = (g * H + j0 + jt * 16 + p) * 16 + q * 4;

  f16x4 xb[2][JT][3];
#pragma unroll
  for (int u = 0; u < 2; u++)
#pragma unroll
    for (int jt = 0; jt < JT; jt++)
#pragma unroll
      for (int g = 0; g < 3; g++)
        xb[u][jt][g] = ld4(xg + sbase + (size_t)u * NO * 16 + loff[jt][g]);

  __syncthreads();

  const int steps = t1 - t0;
#pragma unroll 1
  for (int sb = 0; sb < steps; sb += 2) {
#pragma unroll
    for (int u = 0; u < 2; u++) {   // u compile-time (rule #20)
      const int s = sb + u, t = t0 + s;
      short* hbc = hb + u * 16 * HP;
      short* hbn = hb + (u ^ 1) * 16 * HP;

      f32x4 ar[JT], az[JT], an[JT];
#pragma unroll
      for (int jt = 0; jt < JT; jt++) {
#pragma unroll
        for (int r = 0; r < 4; r++) {
          ar[jt][r] = (float)xb[u][jt][0][r];
          az[jt][r] = (float)xb[u][jt][1][r];
        }
        an[jt] = f32x4{0.f, 0.f, 0.f, 0.f};
      }
#pragma unroll
      for (int k = 0; k < KS; k++) {
        const f16x8 ahk = ld8(&hbc[p * HP + k * 32 + q * 8]);
#pragma unroll
        for (int jt = 0; jt < JT; jt++) {
          ar[jt] = MFMA_F16(ahk, wr[jt][0][k], ar[jt]);
          az[jt] = MFMA_F16(ahk, wr[jt][1][k], az[jt]);
          const f16x8 wnk = ld8(&wn[wrow[jt] * HP + k * 32 + q * 8]);
          an[jt] = MFMA_F16(ahk, wnk, an[jt]);
        }
      }
#pragma unroll
      for (int jt = 0; jt < JT; jt++) {
        const int col = j0 + jt * 16 + p;
#pragma unroll
        for (int r = 0; r < 4; r++) {
          const int bm = q * 4 + r;
          const float rpre = ar[jt][r] + bhr[jt];
          const float zpre = az[jt][r] + bhz[jt];
          const float rg = fast_rcp(1.f + __expf(-rpre));
          const float zg = fast_rcp(1.f + __expf(-zpre));
          const float narg = (float)xb[u][jt][2][r] + rg * (an[jt][r] + bhn[jt]);
          const float e2 = __expf(2.f * narg);
          const float ng = 1.f - 2.f * fast_rcp(e2 + 1.f);  // tanh
          const float hnew = (1.f - zg) * ng + zg * hprev[jt][r];
          hprev[jt][r] = hnew;
          const _Float16 hf = (_Float16)hnew;
          hbn[bm * HP + col] = __builtin_bit_cast(short, hf);
          hseq[((size_t)(b0 + bm) * GT + t) * H + col] = __builtin_bit_cast(short, hf);
        }
      }
      if (t == t1 - 1) {
#pragma unroll
        for (int jt = 0; jt < JT; jt++)
#pragma unroll
          for (int r = 0; r < 4; r++)
            hstate[(size_t)(b0 + q * 4 + r) * H + (j0 + jt * 16 + p)] = hprev[jt][r];
      }
      {  // refill xb[u] for step s+2 (ring has pad for the end overrun)
        const size_t s2 = sbase + (size_t)(s + 2) * NO * 16;
#pragma unroll
        for (int jt = 0; jt < JT; jt++)
#pragma unroll
          for (int g = 0; g < 3; g++)
            xb[u][jt][g] = ld4(xg + s2 + loff[jt][g]);
      }
      barrier_nodrain();
    }
  }
}

// ---------- fused layers 2+3 (round-7/8-proven; r,z biases folded into xg) ----------
__device__ __forceinline__ void rec23_run(const short* __restrict__ xg2,
                                          const short* __restrict__ Whh2,
                                          const float* __restrict__ bhh2,
                                          const short* __restrict__ Wih3,
                                          const short* __restrict__ Whh3,
                                          const float* __restrict__ bih3,
                                          const float* __restrict__ bhh3,
                                          float* __restrict__ hs2,
                                          float* __restrict__ hs3,
                                          int bt, int t0, int t1, int TC,
                                          short* smem, int tid) {
  constexpr int HP2 = H2 + 8, HP3 = H3 + 8, NO = 3 * H2;
  short* hb2 = smem;                 // [2][16][HP2]
  short* hb3 = smem + 2 * 16 * HP2;  // [2][16][HP3]

  const int lane = tid & 63, wid = tid >> 6;
  const int p = lane & 15, q = lane >> 4;
  const int b0 = bt * 16;
  const int col2 = wid * 16 + p;
  const int col3 = (wid & 3) * 16 + p;
  const bool act3 = wid < 4;

  if (t0 == 0) {
    for (int i = tid; i < 2 * 16 * HP2; i += 512) hb2[i] = 0;
    for (int i = tid; i < 2 * 16 * HP3; i += 512) hb3[i] = 0;
  } else {
    for (int i = tid; i < 16 * H2; i += 512) {
      const int r = i / H2, c = i - r * H2;
      hb2[r * HP2 + c] = __builtin_bit_cast(short, (_Float16)hs2[(size_t)(b0 + r) * H2 + c]);
    }
    for (int i = tid; i < 16 * H3; i += 512) {
      const int r = i / H3, c = i - r * H3;
      hb3[r * HP3 + c] = __builtin_bit_cast(short, (_Float16)hs3[(size_t)(b0 + r) * H3 + c]);
    }
  }

  f16x8 w2[3][4];
#pragma unroll
  for (int g = 0; g < 3; g++)
#pragma unroll
    for (int k = 0; k < 4; k++)
      w2[g][k] = ld8(Whh2 + (size_t)(g * H2 + col2) * H2 + k * 32 + q * 8);
  const float bn2 = bhh2[2 * H2 + col2];

  f16x8 wi3[3][4], wh3[3][2];
  float br3 = 0.f, bz3 = 0.f, bn3x = 0.f, bn3h = 0.f;
  if (act3) {
#pragma unroll
    for (int g = 0; g < 3; g++) {
#pragma unroll
      for (int k = 0; k < 4; k++)
        wi3[g][k] = ld8(Wih3 + (size_t)(g * H3 + col3) * H2 + k * 32 + q * 8);
#pragma unroll
      for (int k = 0; k < 2; k++)
        wh3[g][k] = ld8(Whh3 + (size_t)(g * H3 + col3) * H3 + k * 32 + q * 8);
    }
    br3 = bih3[col3] + bhh3[col3];
    bz3 = bih3[H3 + col3] + bhh3[H3 + col3];
    bn3x = bih3[2 * H3 + col3];
    bn3h = bhh3[2 * H3 + col3];
  }

  float h2p[4], h3p[4];
#pragma unroll
  for (int r = 0; r < 4; r++) {
    h2p[r] = (t0 == 0) ? 0.f : hs2[(size_t)(b0 + q * 4 + r) * H2 + col2];
    h3p[r] = (!act3 || t0 == 0) ? 0.f : hs3[(size_t)(b0 + q * 4 + r) * H3 + col3];
  }

  const size_t sbase = (size_t)bt * TC * NO * 16;
  int loff[3];
#pragma unroll
  for (int g = 0; g < 3; g++) loff[g] = (g * H2 + col2) * 16 + q * 4;
  f16x4 xb[2][3];
#pragma unroll
  for (int u = 0; u < 2; u++)
#pragma unroll
    for (int g = 0; g < 3; g++)
      xb[u][g] = ld4(xg2 + sbase + (size_t)u * NO * 16 + loff[g]);

  __syncthreads();

  const int steps = t1 - t0;
#pragma unroll 1
  for (int sb = 0; sb < steps; sb += 2) {
#pragma unroll
    for (int u = 0; u < 2; ++u) {   // u compile-time (rule #20)
      const int s = sb + u, t = t0 + s;
      // ---- layer 2 (all 8 waves); r,z biases already in xg ----
      f32x4 ar, az, an;
#pragma unroll
      for (int r = 0; r < 4; r++) { ar[r] = (float)xb[u][0][r]; az[r] = (float)xb[u][1][r]; }
      an = f32x4{0.f, 0.f, 0.f, 0.f};
#pragma unroll
      for (int k = 0; k < 4; k++) {
        const f16x8 ahk = ld8(&hb2[(u * 16 + p) * HP2 + k * 32 + q * 8]);
        ar = MFMA_F16(ahk, w2[0][k], ar);
        az = MFMA_F16(ahk, w2[1][k], az);
        an = MFMA_F16(ahk, w2[2][k], an);
      }
#pragma unroll
      for (int r = 0; r < 4; r++) {
        const int bm = q * 4 + r;
        const float rg = fast_rcp(1.f + __expf(-ar[r]));
        const float zg = fast_rcp(1.f + __expf(-az[r]));
        const float narg = (float)xb[u][2][r] + rg * (an[r] + bn2);
        const float e2 = __expf(2.f * narg);
        const float ng = 1.f - 2.f * fast_rcp(e2 + 1.f);  // tanh
        const float hnew = (1.f - zg) * ng + zg * h2p[r];
        h2p[r] = hnew;
        hb2[((u ^ 1) * 16 + bm) * HP2 + col2] = __builtin_bit_cast(short, (_Float16)hnew);
        if (t == t1 - 1) hs2[(size_t)(b0 + bm) * H2 + col2] = hnew;
      }
      {  // refill xb[u] for step s+2
        const size_t s2 = sbase + (size_t)(s + 2) * NO * 16;
#pragma unroll
        for (int g = 0; g < 3; g++) xb[u][g] = ld4(xg2 + s2 + loff[g]);
      }
      barrier_nodrain();  // h2(t) visible; refills + stores stay in flight
      // ---- layer 3 (waves 0-3) ----
      if (act3) {
        f32x4 a3r{0.f,0.f,0.f,0.f}, a3z{0.f,0.f,0.f,0.f},
              a3x{0.f,0.f,0.f,0.f}, a3h{0.f,0.f,0.f,0.f};
#pragma unroll
        for (int k = 0; k < 4; k++) {   // input projection from h2(t) in LDS
          const f16x8 a2k = ld8(&hb2[((u ^ 1) * 16 + p) * HP2 + k * 32 + q * 8]);
          a3r = MFMA_F16(a2k, wi3[0][k], a3r);
          a3z = MFMA_F16(a2k, wi3[1][k], a3z);
          a3x = MFMA_F16(a2k, wi3[2][k], a3x);
        }
#pragma unroll
        for (int k = 0; k < 2; k++) {   // recurrence on h3(t-1)
          const f16x8 a3k = ld8(&hb3[(u * 16 + p) * HP3 + k * 32 + q * 8]);
          a3r = MFMA_F16(a3k, wh3[0][k], a3r);
          a3z = MFMA_F16(a3k, wh3[1][k], a3z);
          a3h = MFMA_F16(a3k, wh3[2][k], a3h);
        }
#pragma unroll
        for (int r = 0; r < 4; r++) {
          const int bm = q * 4 + r;
          const float rg = fast_rcp(1.f + __expf(-(a3r[r] + br3)));
          const float zg = fast_rcp(1.f + __expf(-(a3z[r] + bz3)));
          const float narg = a3x[r] + bn3x + rg * (a3h[r] + bn3h);
          const float e2 = __expf(2.f * narg);
          const float ng = 1.f - 2.f * fast_rcp(e2 + 1.f);
          const float hnew = (1.f - zg) * ng + zg * h3p[r];
          h3p[r] = hnew;
          hb3[((u ^ 1) * 16 + bm) * HP3 + col3] = __builtin_bit_cast(short, (_Float16)hnew);
          if (t == t1 - 1) hs3[(size_t)(b0 + bm) * H3 + col3] = hnew;
        }
      }
    }
  }
}

// ---------- fused launches: recurrence chunk c || projection chunk c+1 ----------
__global__ __launch_bounds__(512, 2)
void fused1(const short* __restrict__ xg_rd, short* __restrict__ xg_wr,
            const short* __restrict__ xh, const short* __restrict__ wih1,
            const float* __restrict__ bih1, const short* __restrict__ whh1,
            const float* __restrict__ bhh1, short* __restrict__ h1,
            float* __restrict__ hs1, int t0, int TC) {
  extern __shared__ __align__(16) short smem[];
  if (blockIdx.x < 32) {
    r1_run(xg_rd, whh1, bhh1, h1, hs1, blockIdx.x, t0, t0 + TC, TC, smem, threadIdx.x);
  } else if (xg_wr) {
    const int g = blockIdx.x - 32, nty = TC / 16;
    const int bt = g / nty, ty = g - bt * nty;
    g_body<GF, 3 * H1, 6>(xh, wih1, bih1, xg_wr, TC, bt, ty * 16,
                          t0 + TC + ty * 16, threadIdx.x);
  }
}

__global__ __launch_bounds__(512, 2)
void fused2(const short* __restrict__ xg_rd, short* __restrict__ xg_wr,
            const short* __restrict__ h1, const short* __restrict__ wih2,
            const float* __restrict__ bc2, const short* __restrict__ whh2,
            const float* __restrict__ bhh2, const short* __restrict__ wih3,
            const short* __restrict__ whh3, const float* __restrict__ bih3,
            const float* __restrict__ bhh3, float* __restrict__ hs2,
            float* __restrict__ hs3, int t0, int TC) {
  extern __shared__ __align__(16) short smem[];
  if (blockIdx.x < 32) {
    rec23_run(xg_rd, whh2, bhh2, wih3, whh3, bih3, bhh3, hs2, hs3,
              blockIdx.x, t0, t0 + TC, TC, smem, threadIdx.x);
  } else if (xg_wr) {
    const int g = blockIdx.x - 32, nty = TC / 16;
    const int bt = g / nty, ty = g - bt * nty;
    g_body<H1, 3 * H2, 3>(h1, wih2, bc2, xg_wr, TC, bt, ty * 16,
                          t0 + TC + ty * 16, threadIdx.x);
  }
}

// ---------- dense head ----------
__global__ void dense_kernel(const float* __restrict__ hl, const float* __restrict__ Wd,
                             const float* __restrict__ bd, float* __restrict__ out) {
  const int b = blockIdx.x * 64 + threadIdx.x;
  float a = bd[0];
#pragma unroll
  for (int k = 0; k < 64; k++) a = fmaf(hl[b * 64 + k], Wd[k], a);
  out[b] = a;
}

// ---------- host ----------
extern "C" void kernel_launch(void* const* d_in, const int* in_sizes, int n_in,
                              void* d_out, int out_size, void* d_ws, size_t ws_size,
                              hipStream_t stream) {
  constexpr int B = GB, T = GT, F = GF;
  constexpr int M = B * T;

  const float* x     = (const float*)d_in[0];
  const float* W_ih1 = (const float*)d_in[1];
  const float* W_hh1 = (const float*)d_in[2];
  const float* b_ih1 = (const float*)d_in[3];
  const float* b_hh1 = (const float*)d_in[4];
  const float* W_ih2 = (const float*)d_in[5];
  const float* W_hh2 = (const float*)d_in[6];
  const float* b_ih2 = (const float*)d_in[7];
  const float* b_hh2 = (const float*)d_in[8];
  const float* W_ih3 = (const float*)d_in[9];
  const float* W_hh3 = (const float*)d_in[10];
  const float* b_ih3 = (const float*)d_in[11];
  const float* b_hh3 = (const float*)d_in[12];
  const float* W_d   = (const float*)d_in[13];
  const float* b_d   = (const float*)d_in[14];
  float* out = (float*)d_out;

  char* ws = (char*)d_ws;
  size_t off = 0;
  auto alloc = [&](size_t bytes) -> char* {
    char* pp = ws + off;
    off = (off + bytes + 255) & ~(size_t)255;
    return pp;
  };

  const int nx    = M * F;
  const int nwih1 = 3 * H1 * F,  nwhh1 = 3 * H1 * H1;
  const int nwih2 = 3 * H2 * H1, nwhh2 = 3 * H2 * H2;
  const int nwih3 = 3 * H3 * H2, nwhh3 = 3 * H3 * H3;

  short* xh   = (short*)alloc((size_t)nx * 2);
  short* wih1 = (short*)alloc((size_t)nwih1 * 2);
  short* whh1 = (short*)alloc((size_t)nwhh1 * 2);
  short* wih2 = (short*)alloc((size_t)nwih2 * 2);
  short* whh2 = (short*)alloc((size_t)nwhh2 * 2);
  short* wih3 = (short*)alloc((size_t)nwih3 * 2);
  short* whh3 = (short*)alloc((size_t)nwhh3 * 2);
  short* h1   = (short*)alloc((size_t)M * H1 * 2);
  float* hs1  = (float*)alloc((size_t)B * H1 * 4);
  float* hs2  = (float*)alloc((size_t)B * H2 * 4);
  float* hs3  = (float*)alloc((size_t)B * H3 * 4);
  float* bc2  = (float*)alloc(3 * H2 * 4);
  (void)n_in; (void)in_sizes; (void)out_size;

  // chunk size: double-buffered rings for xg1 (3H1) and xg2 (3H2), +pads
  const size_t avail = (ws_size > off) ? (ws_size - off) : 0;
  int TC = 64;
  auto need = [&](int tc) -> size_t {
    return 2 * ((size_t)32 * tc * (3 * H1) * 16 * 2)
         + 2 * ((size_t)32 * tc * (3 * H2) * 16 * 2) + 2 * 65536;
  };
  while (TC > 16 && need(TC) > avail) TC >>= 1;
  const int NC = T / TC, nty = TC / 16;
  const size_t slot1e = (size_t)32 * TC * (3 * H1) * 16;  // elements
  const size_t slot2e = (size_t)32 * TC * (3 * H2) * 16;
  short* ring1 = (short*)alloc(2 * slot1e * 2 + 65536);
  short* ring2 = (short*)alloc(2 * slot2e * 2 + 65536);

  CastArgs ca;
  ca.d[0] = {x, xh, nx};
  ca.d[1] = {W_ih1, wih1, nwih1};
  ca.d[2] = {W_hh1, whh1, nwhh1};
  ca.d[3] = {W_ih2, wih2, nwih2};
  ca.d[4] = {W_hh2, whh2, nwhh2};
  ca.d[5] = {W_ih3, wih3, nwih3};
  ca.d[6] = {W_hh3, whh3, nwhh3};
  ca.bih2 = b_ih2; ca.bhh2 = b_hh2; ca.bc2 = bc2;
  cast_many<<<1024, 256, 0, stream>>>(ca);

  // LDS: fused1 = wn[256][264] + hb[2][16][264] = 152064 B; fused2 = 13312 B
  constexpr int SM1 = H1 * (H1 + 8) * 2 + 2 * 16 * (H1 + 8) * 2;
  constexpr int SM2 = 2 * 16 * (H2 + 8) * 2 + 2 * 16 * (H3 + 8) * 2;
  (void)hipFuncSetAttribute((const void*)fused1,
                            hipFuncAttributeMaxDynamicSharedMemorySize, SM1);

  // ---- layer 1: r1(c) || g1(c+1) ----
  g_kern<GF, 3 * H1, 6><<<32 * nty, 512, 0, stream>>>(xh, wih1, b_ih1, ring1, TC, 0);
  for (int c = 0; c < NC; ++c) {
    const short* rd = ring1 + (size_t)(c & 1) * slot1e;
    short* wr = (c + 1 < NC) ? ring1 + (size_t)((c + 1) & 1) * slot1e : nullptr;
    fused1<<<32 + (wr ? 32 * nty : 0), 512, SM1, stream>>>(
        rd, wr, xh, wih1, b_ih1, whh1, b_hh1, h1, hs1, c * TC, TC);
  }
  // ---- layers 2+3: rec23(c) || g2(c+1) ----
  g_kern<H1, 3 * H2, 3><<<32 * nty, 512, 0, stream>>>(h1, wih2, bc2, ring2, TC, 0);
  for (int c = 0; c < NC; ++c) {
    const short* rd = ring2 + (size_t)(c & 1) * slot2e;
    short* wr = (c + 1 < NC) ? ring2 + (size_t)((c + 1) & 1) * slot2e : nullptr;
    fused2<<<32 + (wr ? 32 * nty : 0), 512, SM2, stream>>>(
        rd, wr, h1, wih2, bc2, whh2, b_hh2, wih3, whh3, b_ih3, b_hh3,
        hs2, hs3, c * TC, TC);
  }

  dense_kernel<<<B / 64, 64, 0, stream>>>(hs3, W_d, b_d, out);
}

// Round 11
// 767.146 us; speedup vs baseline: 1.6659x; 1.2253x over previous
//
#include <hip/hip_runtime.h>
#include <cstddef>

// ---------- types ----------
typedef _Float16 f16x8 __attribute__((ext_vector_type(8)));
typedef _Float16 f16x4 __attribute__((ext_vector_type(4)));
typedef short    s16x8 __attribute__((ext_vector_type(8)));
typedef short    s16x4 __attribute__((ext_vector_type(4)));
typedef float    f32x4 __attribute__((ext_vector_type(4)));

#define MFMA_F16(a, b, c) __builtin_amdgcn_mfma_f32_16x16x32_f16((a), (b), (c), 0, 0, 0)

constexpr int GB = 512, GT = 256, GF = 64;
constexpr int H1 = 256, H2 = 128, H3 = 64;

#if __has_builtin(__builtin_amdgcn_rcpf)
__device__ __forceinline__ float fast_rcp(float x) { return __builtin_amdgcn_rcpf(x); }
#else
__device__ __forceinline__ float fast_rcp(float x) { return 1.f / x; }
#endif

__device__ __forceinline__ f16x8 ld8(const short* p) {
  return __builtin_bit_cast(f16x8, *(const s16x8*)p);
}
__device__ __forceinline__ f16x4 ld4(const short* p) {
  return __builtin_bit_cast(f16x4, *(const s16x4*)p);
}

// Barrier WITHOUT the vmcnt(0) drain: LDS ordering only, so cross-step global
// prefetches and stores stay in flight.
__device__ __forceinline__ void barrier_nodrain() {
  asm volatile("s_waitcnt lgkmcnt(0)" ::: "memory");
  __builtin_amdgcn_s_barrier();
  asm volatile("" ::: "memory");
}

// ---------- fp32 -> fp16 casts + layer-2 combined bias, one launch ----------
struct CastDesc { const float* src; short* dst; int n; };
struct CastArgs {
  CastDesc d[7];
  const float* bih2; const float* bhh2; float* bc2;
};

__global__ void cast_many(CastArgs a) {
  const int tid = blockIdx.x * blockDim.x + threadIdx.x;
  const int stride = gridDim.x * blockDim.x;
#pragma unroll
  for (int j = 0; j < 7; j++) {
    const float* __restrict__ s = a.d[j].src;
    short* __restrict__ o = a.d[j].dst;
    const int n = a.d[j].n;
    for (int i = tid; i < n; i += stride)
      o[i] = __builtin_bit_cast(short, (_Float16)s[i]);
  }
  for (int i = tid; i < 3 * H2; i += stride)
    a.bc2[i] = a.bih2[i] + (i < 2 * H2 ? a.bhh2[i] : 0.f);
}

// ---------- projection GEMM body (8 waves, 16 timesteps per wg) ----------
template <int K, int NO, int JT>
__device__ __forceinline__ void g_body(const short* __restrict__ A,
                                       const short* __restrict__ W,
                                       const float* __restrict__ biasC,
                                       short* __restrict__ slot, int TC,
                                       int bt, int trel, int tabs, int tid) {
  constexpr int KC = K / 32;
  constexpr int TT = 16;
  const int lane = tid & 63, wid = tid >> 6;
  const int p = lane & 15, q = lane >> 4;
  const int j0 = wid * 16 * JT;

  f16x8 wb[JT][KC];
  float bc[JT];
#pragma unroll
  for (int jt = 0; jt < JT; jt++) {
    const int col = j0 + jt * 16 + p;
    bc[jt] = biasC[col];
#pragma unroll
    for (int kc = 0; kc < KC; kc++)
      wb[jt][kc] = ld8(W + (size_t)col * K + kc * 32 + q * 8);
  }
  const short* arow = A + ((size_t)(bt * 16 + p) * GT + tabs) * K + q * 8;
  short* outb = slot + ((size_t)bt * TC + trel) * NO * 16;

  f16x8 a0[KC], a1[KC];
#pragma unroll
  for (int kc = 0; kc < KC; kc++) a0[kc] = ld8(arow + kc * 32);

  auto step = [&](int ti, f16x8 (&ac)[KC], f16x8 (&anx)[KC], bool pf) {
    if (pf) {
#pragma unroll
      for (int kc = 0; kc < KC; kc++)
        anx[kc] = ld8(arow + (size_t)(ti + 1) * K + kc * 32);
    }
    f32x4 acc[JT];
#pragma unroll
    for (int jt = 0; jt < JT; jt++)
      acc[jt] = f32x4{bc[jt], bc[jt], bc[jt], bc[jt]};
#pragma unroll
    for (int kc = 0; kc < KC; kc++)
#pragma unroll
      for (int jt = 0; jt < JT; jt++)
        acc[jt] = MFMA_F16(ac[kc], wb[jt][kc], acc[jt]);
    short* ob = outb + (size_t)ti * NO * 16;
#pragma unroll
    for (int jt = 0; jt < JT; jt++) {  // C/D: col = lane&15, row = q*4+r
      const int col = j0 + jt * 16 + p;
      s16x4 v;
#pragma unroll
      for (int r = 0; r < 4; r++)
        v[r] = __builtin_bit_cast(short, (_Float16)acc[jt][r]);
      *(s16x4*)&ob[col * 16 + q * 4] = v;
    }
  };

#pragma unroll 1
  for (int ti = 0; ti < TT; ti += 2) {
    step(ti, a0, a1, true);
    step(ti + 1, a1, a0, ti + 2 < TT);
  }
}

template <int K, int NO, int JT>
__global__ __launch_bounds__(512, 2)
void g_kern(const short* __restrict__ A, const short* __restrict__ W,
            const float* __restrict__ biasC, short* __restrict__ slot,
            int TC, int tbase) {
  const int nty = TC / 16;
  const int bt = blockIdx.x / nty, ty = blockIdx.x - bt * nty;
  g_body<K, NO, JT>(A, W, biasC, slot, TC, bt, ty * 16, tbase + ty * 16, threadIdx.x);
}

// ---------- layer-1 recurrence: round-7-proven body ----------
__device__ __forceinline__ void r1_run(const short* __restrict__ xg,
                                       const short* __restrict__ Whh,
                                       const float* __restrict__ bhh,
                                       short* __restrict__ hseq,
                                       float* __restrict__ hstate,
                                       int bt, int t0, int t1, int TC,
                                       short* smem, int tid) {
  constexpr int H = H1, KS = H / 32, JT = 2;
  constexpr int HP = H + 8, NO = 3 * H;

  short* wn = smem;            // [H][HP] full n-gate Whh
  short* hb = smem + H * HP;   // [2][16][HP]

  const int lane = tid & 63, wid = tid >> 6;
  const int p = lane & 15, q = lane >> 4;
  const int b0 = bt * 16, j0 = wid * 16 * JT;

  {  // stage n-gate rows of Whh into LDS (one-time per chunk)
    constexpr int KV = H / 8;
    for (int i = tid; i < H * KV; i += 512) {
      const int row = i / KV, kc = i - row * KV;
      *(s16x8*)&wn[row * HP + kc * 8] =
          *(const s16x8*)&Whh[(size_t)(2 * H + row) * H + kc * 8];
    }
  }
  if (t0 == 0) {
    for (int i = tid; i < 16 * HP; i += 512) hb[i] = 0;
  } else {
    for (int i = tid; i < 16 * H; i += 512) {
      const int row = i / H, col = i - row * H;
      hb[row * HP + col] =
          __builtin_bit_cast(short, (_Float16)hstate[(size_t)(b0 + row) * H + col]);
    }
  }

  f16x8 wr[JT][2][KS];
#pragma unroll
  for (int jt = 0; jt < JT; jt++) {
    const int col = j0 + jt * 16 + p;
#pragma unroll
    for (int g = 0; g < 2; g++)
#pragma unroll
      for (int k = 0; k < KS; k++)
        wr[jt][g][k] = ld8(Whh + (size_t)(g * H + col) * H + k * 32 + q * 8);
  }
  float bhr[JT], bhz[JT], bhn[JT];
  int wrow[JT];
#pragma unroll
  for (int jt = 0; jt < JT; jt++) {
    const int col = j0 + jt * 16 + p;
    wrow[jt] = col;
    bhr[jt] = bhh[col];
    bhz[jt] = bhh[H + col];
    bhn[jt] = bhh[2 * H + col];
  }

  float hprev[JT][4];
#pragma unroll
  for (int jt = 0; jt < JT; jt++)
#pragma unroll
    for (int r = 0; r < 4; r++)
      hprev[jt][r] = (t0 == 0) ? 0.f
                   : hstate[(size_t)(b0 + q * 4 + r) * H + (j0 + jt * 16 + p)];

  const size_t sbase = (size_t)bt * TC * NO * 16;
  int loff[JT][3];
#pragma unroll
  for (int jt = 0; jt < JT; jt++)
#pragma unroll
    for (int g = 0; g < 3; g++)
      loff[jt][g] = (g * H + j0 + jt * 16 + p) * 16 + q * 4;

  f16x4 xb[2][JT][3];
#pragma unroll
  for (int u = 0; u < 2; u++)
#pragma unroll
    for (int jt = 0; jt < JT; jt++)
#pragma unroll
      for (int g = 0; g < 3; g++)
        xb[u][jt][g] = ld4(xg + sbase + (size_t)u * NO * 16 + loff[jt][g]);

  __syncthreads();

  const int steps = t1 - t0;
#pragma unroll 1
  for (int sb = 0; sb < steps; sb += 2) {
#pragma unroll
    for (int u = 0; u < 2; u++) {   // u compile-time (rule #20)
      const int s = sb + u, t = t0 + s;
      short* hbc = hb + u * 16 * HP;
      short* hbn = hb + (u ^ 1) * 16 * HP;

      f32x4 ar[JT], az[JT], an[JT];
#pragma unroll
      for (int jt = 0; jt < JT; jt++) {
#pragma unroll
        for (int r = 0; r < 4; r++) {
          ar[jt][r] = (float)xb[u][jt][0][r];
          az[jt][r] = (float)xb[u][jt][1][r];
        }
        an[jt] = f32x4{0.f, 0.f, 0.f, 0.f};
      }
#pragma unroll
      for (int k = 0; k < KS; k++) {
        const f16x8 ahk = ld8(&hbc[p * HP + k * 32 + q * 8]);
#pragma unroll
        for (int jt = 0; jt < JT; jt++) {
          ar[jt] = MFMA_F16(ahk, wr[jt][0][k], ar[jt]);
          az[jt] = MFMA_F16(ahk, wr[jt][1][k], az[jt]);
          const f16x8 wnk = ld8(&wn[wrow[jt] * HP + k * 32 + q * 8]);
          an[jt] = MFMA_F16(ahk, wnk, an[jt]);
        }
      }
#pragma unroll
      for (int jt = 0; jt < JT; jt++) {
        const int col = j0 + jt * 16 + p;
#pragma unroll
        for (int r = 0; r < 4; r++) {
          const int bm = q * 4 + r;
          const float rpre = ar[jt][r] + bhr[jt];
          const float zpre = az[jt][r] + bhz[jt];
          const float rg = fast_rcp(1.f + __expf(-rpre));
          const float zg = fast_rcp(1.f + __expf(-zpre));
          const float narg = (float)xb[u][jt][2][r] + rg * (an[jt][r] + bhn[jt]);
          const float e2 = __expf(2.f * narg);
          const float ng = 1.f - 2.f * fast_rcp(e2 + 1.f);  // tanh
          const float hnew = (1.f - zg) * ng + zg * hprev[jt][r];
          hprev[jt][r] = hnew;
          const _Float16 hf = (_Float16)hnew;
          hbn[bm * HP + col] = __builtin_bit_cast(short, hf);
          hseq[((size_t)(b0 + bm) * GT + t) * H + col] = __builtin_bit_cast(short, hf);
        }
      }
      if (t == t1 - 1) {
#pragma unroll
        for (int jt = 0; jt < JT; jt++)
#pragma unroll
          for (int r = 0; r < 4; r++)
            hstate[(size_t)(b0 + q * 4 + r) * H + (j0 + jt * 16 + p)] = hprev[jt][r];
      }
      {  // refill xb[u] for step s+2 (ring has pad for the end overrun)
        const size_t s2 = sbase + (size_t)(s + 2) * NO * 16;
#pragma unroll
        for (int jt = 0; jt < JT; jt++)
#pragma unroll
          for (int g = 0; g < 3; g++)
            xb[u][jt][g] = ld4(xg + s2 + loff[jt][g]);
      }
      barrier_nodrain();
    }
  }
}

// ---------- fused layers 2+3 (round-7-proven; r,z biases folded into xg) ----------
__device__ __forceinline__ void rec23_run(const short* __restrict__ xg2,
                                          const short* __restrict__ Whh2,
                                          const float* __restrict__ bhh2,
                                          const short* __restrict__ Wih3,
                                          const short* __restrict__ Whh3,
                                          const float* __restrict__ bih3,
                                          const float* __restrict__ bhh3,
                                          float* __restrict__ hs2,
                                          float* __restrict__ hs3,
                                          int bt, int t0, int t1, int TC,
                                          short* smem, int tid) {
  constexpr int HP2 = H2 + 8, HP3 = H3 + 8, NO = 3 * H2;
  short* hb2 = smem;                 // [2][16][HP2]
  short* hb3 = smem + 2 * 16 * HP2;  // [2][16][HP3]

  const int lane = tid & 63, wid = tid >> 6;
  const int p = lane & 15, q = lane >> 4;
  const int b0 = bt * 16;
  const int col2 = wid * 16 + p;
  const int col3 = (wid & 3) * 16 + p;
  const bool act3 = wid < 4;

  if (t0 == 0) {
    for (int i = tid; i < 2 * 16 * HP2; i += 512) hb2[i] = 0;
    for (int i = tid; i < 2 * 16 * HP3; i += 512) hb3[i] = 0;
  } else {
    for (int i = tid; i < 16 * H2; i += 512) {
      const int r = i / H2, c = i - r * H2;
      hb2[r * HP2 + c] = __builtin_bit_cast(short, (_Float16)hs2[(size_t)(b0 + r) * H2 + c]);
    }
    for (int i = tid; i < 16 * H3; i += 512) {
      const int r = i / H3, c = i - r * H3;
      hb3[r * HP3 + c] = __builtin_bit_cast(short, (_Float16)hs3[(size_t)(b0 + r) * H3 + c]);
    }
  }

  f16x8 w2[3][4];
#pragma unroll
  for (int g = 0; g < 3; g++)
#pragma unroll
    for (int k = 0; k < 4; k++)
      w2[g][k] = ld8(Whh2 + (size_t)(g * H2 + col2) * H2 + k * 32 + q * 8);
  const float bn2 = bhh2[2 * H2 + col2];

  f16x8 wi3[3][4], wh3[3][2];
  float br3 = 0.f, bz3 = 0.f, bn3x = 0.f, bn3h = 0.f;
  if (act3) {
#pragma unroll
    for (int g = 0; g < 3; g++) {
#pragma unroll
      for (int k = 0; k < 4; k++)
        wi3[g][k] = ld8(Wih3 + (size_t)(g * H3 + col3) * H2 + k * 32 + q * 8);
#pragma unroll
      for (int k = 0; k < 2; k++)
        wh3[g][k] = ld8(Whh3 + (size_t)(g * H3 + col3) * H3 + k * 32 + q * 8);
    }
    br3 = bih3[col3] + bhh3[col3];
    bz3 = bih3[H3 + col3] + bhh3[H3 + col3];
    bn3x = bih3[2 * H3 + col3];
    bn3h = bhh3[2 * H3 + col3];
  }

  float h2p[4], h3p[4];
#pragma unroll
  for (int r = 0; r < 4; r++) {
    h2p[r] = (t0 == 0) ? 0.f : hs2[(size_t)(b0 + q * 4 + r) * H2 + col2];
    h3p[r] = (!act3 || t0 == 0) ? 0.f : hs3[(size_t)(b0 + q * 4 + r) * H3 + col3];
  }

  const size_t sbase = (size_t)bt * TC * NO * 16;
  int loff[3];
#pragma unroll
  for (int g = 0; g < 3; g++) loff[g] = (g * H2 + col2) * 16 + q * 4;
  f16x4 xb[2][3];
#pragma unroll
  for (int u = 0; u < 2; u++)
#pragma unroll
    for (int g = 0; g < 3; g++)
      xb[u][g] = ld4(xg2 + sbase + (size_t)u * NO * 16 + loff[g]);

  __syncthreads();

  const int steps = t1 - t0;
#pragma unroll 1
  for (int sb = 0; sb < steps; sb += 2) {
#pragma unroll
    for (int u = 0; u < 2; ++u) {   // u compile-time (rule #20)
      const int s = sb + u, t = t0 + s;
      // ---- layer 2 (all 8 waves); r,z biases already in xg ----
      f32x4 ar, az, an;
#pragma unroll
      for (int r = 0; r < 4; r++) { ar[r] = (float)xb[u][0][r]; az[r] = (float)xb[u][1][r]; }
      an = f32x4{0.f, 0.f, 0.f, 0.f};
#pragma unroll
      for (int k = 0; k < 4; k++) {
        const f16x8 ahk = ld8(&hb2[(u * 16 + p) * HP2 + k * 32 + q * 8]);
        ar = MFMA_F16(ahk, w2[0][k], ar);
        az = MFMA_F16(ahk, w2[1][k], az);
        an = MFMA_F16(ahk, w2[2][k], an);
      }
#pragma unroll
      for (int r = 0; r < 4; r++) {
        const int bm = q * 4 + r;
        const float rg = fast_rcp(1.f + __expf(-ar[r]));
        const float zg = fast_rcp(1.f + __expf(-az[r]));
        const float narg = (float)xb[u][2][r] + rg * (an[r] + bn2);
        const float e2 = __expf(2.f * narg);
        const float ng = 1.f - 2.f * fast_rcp(e2 + 1.f);  // tanh
        const float hnew = (1.f - zg) * ng + zg * h2p[r];
        h2p[r] = hnew;
        hb2[((u ^ 1) * 16 + bm) * HP2 + col2] = __builtin_bit_cast(short, (_Float16)hnew);
        if (t == t1 - 1) hs2[(size_t)(b0 + bm) * H2 + col2] = hnew;
      }
      {  // refill xb[u] for step s+2
        const size_t s2 = sbase + (size_t)(s + 2) * NO * 16;
#pragma unroll
        for (int g = 0; g < 3; g++) xb[u][g] = ld4(xg2 + s2 + loff[g]);
      }
      barrier_nodrain();  // h2(t) visible; refills + stores stay in flight
      // ---- layer 3 (waves 0-3) ----
      if (act3) {
        f32x4 a3r{0.f,0.f,0.f,0.f}, a3z{0.f,0.f,0.f,0.f},
              a3x{0.f,0.f,0.f,0.f}, a3h{0.f,0.f,0.f,0.f};
#pragma unroll
        for (int k = 0; k < 4; k++) {   // input projection from h2(t) in LDS
          const f16x8 a2k = ld8(&hb2[((u ^ 1) * 16 + p) * HP2 + k * 32 + q * 8]);
          a3r = MFMA_F16(a2k, wi3[0][k], a3r);
          a3z = MFMA_F16(a2k, wi3[1][k], a3z);
          a3x = MFMA_F16(a2k, wi3[2][k], a3x);
        }
#pragma unroll
        for (int k = 0; k < 2; k++) {   // recurrence on h3(t-1)
          const f16x8 a3k = ld8(&hb3[(u * 16 + p) * HP3 + k * 32 + q * 8]);
          a3r = MFMA_F16(a3k, wh3[0][k], a3r);
          a3z = MFMA_F16(a3k, wh3[1][k], a3z);
          a3h = MFMA_F16(a3k, wh3[2][k], a3h);
        }
#pragma unroll
        for (int r = 0; r < 4; r++) {
          const int bm = q * 4 + r;
          const float rg = fast_rcp(1.f + __expf(-(a3r[r] + br3)));
          const float zg = fast_rcp(1.f + __expf(-(a3z[r] + bz3)));
          const float narg = a3x[r] + bn3x + rg * (a3h[r] + bn3h);
          const float e2 = __expf(2.f * narg);
          const float ng = 1.f - 2.f * fast_rcp(e2 + 1.f);
          const float hnew = (1.f - zg) * ng + zg * h3p[r];
          h3p[r] = hnew;
          hb3[((u ^ 1) * 16 + bm) * HP3 + col3] = __builtin_bit_cast(short, (_Float16)hnew);
          if (t == t1 - 1) hs3[(size_t)(b0 + bm) * H3 + col3] = hnew;
        }
      }
    }
  }
}

// ---------- cross-layer wavefront launch ----------
// Launch c runs, CONCURRENTLY on disjoint wgs (deps all from launches <= c-1,
// ordered by kernel boundaries; no flags):
//   rec1(c)      <- ring1 slot c&1      (g1 in launch c-1 / primer)
//   g1(c+1)      -> ring1 slot (c+1)&1
//   g2(c-1)      <- h1 chunk c-1        (rec1 in launch c-1); -> ring2 (c-1)&1
//   rec23(c-2)   <- ring2 slot (c-2)&1  (g2 in launch c-1)
// h1 write (chunk c) and read (chunk c-1) regions are disjoint.
struct PipeArgs {
  const short* xh;
  const short* wih1; const short* whh1; const float* bih1; const float* bhh1;
  const short* wih2; const float* bc2;  const short* whh2; const float* bhh2;
  const short* wih3; const short* whh3; const float* bih3; const float* bhh3;
  short* h1; float* hs1; float* hs2; float* hs3;
  short* ring1; short* ring2;
  size_t slot1e, slot2e;
  int c, NC, TC;
};

__global__ __launch_bounds__(512, 2)
void fused_all(PipeArgs a) {
  extern __shared__ __align__(16) short smem[];
  const int nty = a.TC / 16, GW = 32 * nty;
  const int bid = blockIdx.x, tid = threadIdx.x;
  if (bid < 32) {                       // rec1(c)
    if (a.c < a.NC)
      r1_run(a.ring1 + (size_t)(a.c & 1) * a.slot1e, a.whh1, a.bhh1, a.h1, a.hs1,
             bid, a.c * a.TC, (a.c + 1) * a.TC, a.TC, smem, tid);
  } else if (bid < 64) {                // rec23(c-2)
    const int cc = a.c - 2;
    if (cc >= 0 && cc < a.NC)
      rec23_run(a.ring2 + (size_t)(cc & 1) * a.slot2e, a.whh2, a.bhh2,
                a.wih3, a.whh3, a.bih3, a.bhh3, a.hs2, a.hs3,
                bid - 32, cc * a.TC, (cc + 1) * a.TC, a.TC, smem, tid);
  } else if (bid < 64 + GW) {           // g1(c+1)
    const int cc = a.c + 1;
    if (cc < a.NC) {
      const int g = bid - 64, bt = g / nty, ty = g - bt * nty;
      g_body<GF, 3 * H1, 6>(a.xh, a.wih1, a.bih1,
                            a.ring1 + (size_t)(cc & 1) * a.slot1e, a.TC,
                            bt, ty * 16, cc * a.TC + ty * 16, tid);
    }
  } else {                              // g2(c-1)
    const int cc = a.c - 1;
    if (cc >= 0 && cc < a.NC) {
      const int g = bid - 64 - GW, bt = g / nty, ty = g - bt * nty;
      g_body<H1, 3 * H2, 3>(a.h1, a.wih2, a.bc2,
                            a.ring2 + (size_t)(cc & 1) * a.slot2e, a.TC,
                            bt, ty * 16, cc * a.TC + ty * 16, tid);
    }
  }
}

// ---------- dense head ----------
__global__ void dense_kernel(const float* __restrict__ hl, const float* __restrict__ Wd,
                             const float* __restrict__ bd, float* __restrict__ out) {
  const int b = blockIdx.x * 64 + threadIdx.x;
  float a = bd[0];
#pragma unroll
  for (int k = 0; k < 64; k++) a = fmaf(hl[b * 64 + k], Wd[k], a);
  out[b] = a;
}

// ---------- host ----------
extern "C" void kernel_launch(void* const* d_in, const int* in_sizes, int n_in,
                              void* d_out, int out_size, void* d_ws, size_t ws_size,
                              hipStream_t stream) {
  constexpr int B = GB, T = GT, F = GF;
  constexpr int M = B * T;

  const float* x     = (const float*)d_in[0];
  const float* W_ih1 = (const float*)d_in[1];
  const float* W_hh1 = (const float*)d_in[2];
  const float* b_ih1 = (const float*)d_in[3];
  const float* b_hh1 = (const float*)d_in[4];
  const float* W_ih2 = (const float*)d_in[5];
  const float* W_hh2 = (const float*)d_in[6];
  const float* b_ih2 = (const float*)d_in[7];
  const float* b_hh2 = (const float*)d_in[8];
  const float* W_ih3 = (const float*)d_in[9];
  const float* W_hh3 = (const float*)d_in[10];
  const float* b_ih3 = (const float*)d_in[11];
  const float* b_hh3 = (const float*)d_in[12];
  const float* W_d   = (const float*)d_in[13];
  const float* b_d   = (const float*)d_in[14];
  float* out = (float*)d_out;

  char* ws = (char*)d_ws;
  size_t off = 0;
  auto alloc = [&](size_t bytes) -> char* {
    char* pp = ws + off;
    off = (off + bytes + 255) & ~(size_t)255;
    return pp;
  };

  const int nx    = M * F;
  const int nwih1 = 3 * H1 * F,  nwhh1 = 3 * H1 * H1;
  const int nwih2 = 3 * H2 * H1, nwhh2 = 3 * H2 * H2;
  const int nwih3 = 3 * H3 * H2, nwhh3 = 3 * H3 * H3;

  short* xh   = (short*)alloc((size_t)nx * 2);
  short* wih1 = (short*)alloc((size_t)nwih1 * 2);
  short* whh1 = (short*)alloc((size_t)nwhh1 * 2);
  short* wih2 = (short*)alloc((size_t)nwih2 * 2);
  short* whh2 = (short*)alloc((size_t)nwhh2 * 2);
  short* wih3 = (short*)alloc((size_t)nwih3 * 2);
  short* whh3 = (short*)alloc((size_t)nwhh3 * 2);
  short* h1   = (short*)alloc((size_t)M * H1 * 2);
  float* hs1  = (float*)alloc((size_t)B * H1 * 4);
  float* hs2  = (float*)alloc((size_t)B * H2 * 4);
  float* hs3  = (float*)alloc((size_t)B * H3 * 4);
  float* bc2  = (float*)alloc(3 * H2 * 4);
  (void)n_in; (void)in_sizes; (void)out_size;

  // chunk size: double-buffered rings for xg1 (3H1) and xg2 (3H2), +pads
  const size_t avail = (ws_size > off) ? (ws_size - off) : 0;
  int TC = 64;
  auto need = [&](int tc) -> size_t {
    return 2 * ((size_t)32 * tc * (3 * H1) * 16 * 2)
         + 2 * ((size_t)32 * tc * (3 * H2) * 16 * 2) + 2 * 65536;
  };
  while (TC > 16 && need(TC) > avail) TC >>= 1;
  const int NC = T / TC, nty = TC / 16;
  const size_t slot1e = (size_t)32 * TC * (3 * H1) * 16;  // elements
  const size_t slot2e = (size_t)32 * TC * (3 * H2) * 16;
  short* ring1 = (short*)alloc(2 * slot1e * 2 + 65536);
  short* ring2 = (short*)alloc(2 * slot2e * 2 + 65536);

  CastArgs ca;
  ca.d[0] = {x, xh, nx};
  ca.d[1] = {W_ih1, wih1, nwih1};
  ca.d[2] = {W_hh1, whh1, nwhh1};
  ca.d[3] = {W_ih2, wih2, nwih2};
  ca.d[4] = {W_hh2, whh2, nwhh2};
  ca.d[5] = {W_ih3, wih3, nwih3};
  ca.d[6] = {W_hh3, whh3, nwhh3};
  ca.bih2 = b_ih2; ca.bhh2 = b_hh2; ca.bc2 = bc2;
  cast_many<<<1024, 256, 0, stream>>>(ca);

  // LDS: max over stages = r1: wn[256][264] + hb[2][16][264] = 152064 B
  constexpr int SM1 = H1 * (H1 + 8) * 2 + 2 * 16 * (H1 + 8) * 2;
  (void)hipFuncSetAttribute((const void*)fused_all,
                            hipFuncAttributeMaxDynamicSharedMemorySize, SM1);

  // prime ring1 chunk 0
  g_kern<GF, 3 * H1, 6><<<32 * nty, 512, 0, stream>>>(xh, wih1, b_ih1, ring1, TC, 0);

  PipeArgs pa;
  pa.xh = xh;
  pa.wih1 = wih1; pa.whh1 = whh1; pa.bih1 = b_ih1; pa.bhh1 = b_hh1;
  pa.wih2 = wih2; pa.bc2 = bc2;   pa.whh2 = whh2; pa.bhh2 = b_hh2;
  pa.wih3 = wih3; pa.whh3 = whh3; pa.bih3 = b_ih3; pa.bhh3 = b_hh3;
  pa.h1 = h1; pa.hs1 = hs1; pa.hs2 = hs2; pa.hs3 = hs3;
  pa.ring1 = ring1; pa.ring2 = ring2;
  pa.slot1e = slot1e; pa.slot2e = slot2e;
  pa.NC = NC; pa.TC = TC;

  const int grid = 64 + 2 * (32 * nty);
  for (int c = 0; c <= NC + 1; ++c) {   // NC+2 wavefront launches
    pa.c = c;
    fused_all<<<grid, 512, SM1, stream>>>(pa);
  }

  dense_kernel<<<B / 64, 64, 0, stream>>>(hs3, W_d, b_d, out);
}